// Round 8
// baseline (1827.603 us; speedup 1.0000x reference)
//
#include <hip/hip_runtime.h>

// EntropicOTQuantileRegression — R8: barrier-free per-wave strips.
// Each wave owns 16 j end-to-end: layer0 in regs -> L1 MFMA -> (C-frags ARE
// L2 B-frags via W2 row-permutation rho at staging) -> L2 MFMA -> psi ->
// per-wave online LSE. W hi/lo frags in LDS fragment-linear (conflict-free
// lane-linear ds_read_b128). Zero __syncthreads in the main loop.

#define NPTS 1024
#define FDIM 64
#define RDIM 8
#define HID  128
#define NTH  512
#define NW   8
#define JW   16
#define NPASS (NPTS / (NW * JW))   // 8
#define EPS_F 0.1f
#define INV_EPS 10.0f

typedef __attribute__((ext_vector_type(8))) short short8;   // 8 bf16
typedef __attribute__((ext_vector_type(4))) float f32x4;

// LDS byte offsets
#define OFF_WF1  0         // 65536: W1 frags [mt8][ks4][hi/lo][lane*16]
#define OFF_WF2  65536     // 65536: W2 frags (rho-permuted k rows)
#define OFF_STG  131072    // 16384: init staging chunk (32 rows x 128 f32)
#define OFF_HXI  147456    // 512
#define OFF_B1   147968    // 512
#define OFF_B2   148480    // 512
#define OFF_WOUT 148992    // 512
#define OFF_W0R  149504    // 4096 (fallback only)
#define OFF_LSE  153600    // 64
#define LDS_BYTES 153664   // < 163840

__device__ __forceinline__ float sp(float x) {
    return fmaxf(x, 0.0f) + __logf(1.0f + __expf(-fabsf(x)));
}
__device__ __forceinline__ unsigned bcu(float x) { return __builtin_bit_cast(unsigned, x); }
__device__ __forceinline__ float bcf(unsigned x) { return __builtin_bit_cast(float, x); }
__device__ __forceinline__ unsigned short bf16rne(float x) {
    unsigned u = bcu(x);
    return (unsigned short)((u + 0x7FFFu + ((u >> 16) & 1u)) >> 16);
}
__device__ __forceinline__ void hilo(float x, unsigned short& h, unsigned short& l) {
    unsigned u = bcu(x);
    unsigned hb = (u + 0x7FFFu + ((u >> 16) & 1u)) & 0xFFFF0000u;
    h = (unsigned short)(hb >> 16);
    l = bf16rne(x - bcf(hb));
}

// pre-kernel: hX[n][c] natural; hY in the coalesced frag-read layout:
// hYP[(n>>4)*2048 + (c>>2)*64 + (n&15)*4 + (c&3)]
__global__ void eotqr_pre(const float* __restrict__ Xg, const float* __restrict__ Yg,
                          const float* __restrict__ W0g, const float* __restrict__ b0g,
                          float* __restrict__ hX, float* __restrict__ hYP) {
    const int n = blockIdx.x, c = threadIdx.x;
    float a = b0g[c];
    for (int f = 0; f < FDIM; ++f) a += Xg[n * FDIM + f] * W0g[f * HID + c];
    hX[n * HID + c] = a;
    float b = 0.0f;
#pragma unroll
    for (int r = 0; r < RDIM; ++r) b += Yg[n * RDIM + r] * W0g[(FDIM + r) * HID + c];
    hYP[(n >> 4) * 2048 + (c >> 2) * 64 + (n & 15) * 4 + (c & 3)] = b;
}

// Stage one layer's W into frag-linear LDS. Chunk r = raw rows [32r,32r+32)
// == frags ks=r. Wave w builds mt=w. IS_W2 applies rho (layer1-C == layer2-B).
#define STAGE_LAYER(WSRC, WFBASE, IS_W2)                                      \
    for (int r = 0; r < 4; ++r) {                                             \
        __syncthreads();                                                      \
        for (int e4 = tid; e4 < 1024; e4 += NTH)                              \
            ((float4*)(smem + OFF_STG))[e4] =                                 \
                ((const float4*)((WSRC) + r * 32 * HID))[e4];                 \
        __syncthreads();                                                      \
        {                                                                     \
            const float* stg = (const float*)(smem + OFF_STG);                \
            const int mt = wid;                                               \
            union { unsigned short u[8]; short8 v; } ph, pl;                  \
            _Pragma("unroll")                                                 \
            for (int e = 0; e < 8; ++e) {                                     \
                const int kloc = (IS_W2) ? ((e >= 4) * 16 + g * 4 + (e & 3))  \
                                         : (g * 8 + e);                       \
                hilo(stg[kloc * HID + mt * 16 + (lane & 15)], ph.u[e], pl.u[e]); \
            }                                                                 \
            *(short8*)(smem + (WFBASE) + ((mt * 4 + r) * 2 + 0) * 1024 + lane * 16) = ph.v; \
            *(short8*)(smem + (WFBASE) + ((mt * 4 + r) * 2 + 1) * 1024 + lane * 16) = pl.v; \
        }                                                                     \
    }

#define GEMM_LAYER(WFBASE)                                                    \
    _Pragma("unroll")                                                         \
    for (int mt = 0; mt < 8; ++mt) acc[mt] = f32x4{0.f, 0.f, 0.f, 0.f};       \
    _Pragma("unroll")                                                         \
    for (int mt = 0; mt < 8; ++mt) {                                          \
        _Pragma("unroll")                                                     \
        for (int ks = 0; ks < 4; ++ks) {                                      \
            const short8 ah = *(const short8*)(smem + (WFBASE) + ((mt * 4 + ks) * 2 + 0) * 1024 + lane * 16); \
            const short8 al = *(const short8*)(smem + (WFBASE) + ((mt * 4 + ks) * 2 + 1) * 1024 + lane * 16); \
            acc[mt] = __builtin_amdgcn_mfma_f32_16x16x32_bf16(ah, bh[ks], acc[mt], 0, 0, 0); \
            acc[mt] = __builtin_amdgcn_mfma_f32_16x16x32_bf16(al, bh[ks], acc[mt], 0, 0, 0); \
            acc[mt] = __builtin_amdgcn_mfma_f32_16x16x32_bf16(ah, bl[ks], acc[mt], 0, 0, 0); \
        }                                                                     \
    }

template <bool USE_WS>
__global__
__attribute__((amdgpu_flat_work_group_size(NTH, NTH)))
__attribute__((amdgpu_waves_per_eu(1, 2)))
void eotqr_mfma(const float* __restrict__ Xg, const float* __restrict__ Ug,
                const float* __restrict__ Yg, const float* __restrict__ W0g,
                const float* __restrict__ b0g, const float* __restrict__ W1g,
                const float* __restrict__ b1g, const float* __restrict__ W2g,
                const float* __restrict__ b2g, const float* __restrict__ Woutg,
                const float* __restrict__ boutg, const float* __restrict__ hXg,
                const float* __restrict__ hYg, float* __restrict__ outg) {
    extern __shared__ __align__(16) char smem[];
    const int tid  = threadIdx.x;
    const int i    = blockIdx.x;
    const int lane = tid & 63;
    const int wid  = tid >> 6;
    const int g    = lane >> 4;

    // ---- init: small tables ----
    if (tid < HID) {
        ((float*)(smem + OFF_B1))[tid]   = b1g[tid];
        ((float*)(smem + OFF_B2))[tid]   = b2g[tid];
        ((float*)(smem + OFF_WOUT))[tid] = Woutg[tid];
        float a;
        if (USE_WS) {
            a = hXg[i * HID + tid];
        } else {
            a = b0g[tid];
            for (int f = 0; f < FDIM; ++f) a += Xg[i * FDIM + f] * W0g[f * HID + tid];
        }
        ((float*)(smem + OFF_HXI))[tid] = a;
    }
    if (!USE_WS)
        for (int e = tid; e < RDIM * HID; e += NTH)
            ((float*)(smem + OFF_W0R))[e] = W0g[FDIM * HID + e];

    // ---- stage W frags (the only barriers besides the final combine) ----
    STAGE_LAYER(W1g, OFF_WF1, 0)
    STAGE_LAYER(W2g, OFF_WF2, 1)
    __syncthreads();

    const float bout0 = boutg[0];
    float Ui[RDIM];
#pragma unroll
    for (int r = 0; r < RDIM; ++r) Ui[r] = Ug[i * RDIM + r];

    float m_run = -INFINITY, s_run = 0.0f;

#pragma unroll 1
    for (int p = 0; p < NPASS; ++p) {
        const int jme = p * (NW * JW) + wid * JW + (lane & 15);  // this lane's j
        // Y row (for fallback hY and for the cost dot)
        const float4 ya = *(const float4*)(Yg + jme * RDIM);
        const float4 yb = *(const float4*)(Yg + jme * RDIM + 4);

        // ---- layer 0: B1 frags in registers ----
        short8 bh[4], bl[4];
#pragma unroll
        for (int ks = 0; ks < 4; ++ks) {
            float s[8];
            if (USE_WS) {
                const float* hb = hYg + (size_t)(p * NW + wid) * 2048 + (lane & 15) * 4;
                const float4 q0 = *(const float4*)(hb + (8 * ks + 2 * g + 0) * 64);
                const float4 q1 = *(const float4*)(hb + (8 * ks + 2 * g + 1) * 64);
                s[0] = q0.x; s[1] = q0.y; s[2] = q0.z; s[3] = q0.w;
                s[4] = q1.x; s[5] = q1.y; s[6] = q1.z; s[7] = q1.w;
            } else {
                const float* w0r = (const float*)(smem + OFF_W0R);
                const float yv[8] = {ya.x, ya.y, ya.z, ya.w, yb.x, yb.y, yb.z, yb.w};
#pragma unroll
                for (int e = 0; e < 8; ++e) {
                    float b = 0.0f;
#pragma unroll
                    for (int r = 0; r < RDIM; ++r)
                        b += yv[r] * w0r[r * HID + 32 * ks + 8 * g + e];
                    s[e] = b;
                }
            }
            const float4 hx0 = *(const float4*)(smem + OFF_HXI + (32 * ks + 8 * g) * 4);
            const float4 hx1 = *(const float4*)(smem + OFF_HXI + (32 * ks + 8 * g) * 4 + 16);
            s[0] += hx0.x; s[1] += hx0.y; s[2] += hx0.z; s[3] += hx0.w;
            s[4] += hx1.x; s[5] += hx1.y; s[6] += hx1.z; s[7] += hx1.w;
            union { unsigned short u[8]; short8 v; } ph, pl;
#pragma unroll
            for (int e = 0; e < 8; ++e) hilo(sp(s[e]), ph.u[e], pl.u[e]);
            bh[ks] = ph.v; bl[ks] = pl.v;
        }

        f32x4 acc[8];
        // ---- layer 1 ----
        GEMM_LAYER(OFF_WF1)

        // ---- epi1: C-frags -> B2 frags in-lane (rho handled at W2 staging) ----
#pragma unroll
        for (int ks = 0; ks < 4; ++ks) {
            union { unsigned short u[8]; short8 v; } ph, pl;
#pragma unroll
            for (int b = 0; b < 2; ++b) {
                const int mt = 2 * ks + b;
                const float4 bias = *(const float4*)(smem + OFF_B1 + (mt * 16 + 4 * g) * 4);
                const float bv[4] = {bias.x, bias.y, bias.z, bias.w};
#pragma unroll
                for (int e2 = 0; e2 < 4; ++e2)
                    hilo(sp(acc[mt][e2] + bv[e2]), ph.u[b * 4 + e2], pl.u[b * 4 + e2]);
            }
            bh[ks] = ph.v; bl[ks] = pl.v;
        }

        // ---- layer 2 ----
        GEMM_LAYER(OFF_WF2)

        // ---- epi2: psi partial over this lane's rows ----
        float ps = 0.0f;
#pragma unroll
        for (int mt = 0; mt < 8; ++mt) {
            const float4 b2v = *(const float4*)(smem + OFF_B2 + (mt * 16 + 4 * g) * 4);
            const float4 wov = *(const float4*)(smem + OFF_WOUT + (mt * 16 + 4 * g) * 4);
            const float bv[4] = {b2v.x, b2v.y, b2v.z, b2v.w};
            const float wv[4] = {wov.x, wov.y, wov.z, wov.w};
#pragma unroll
            for (int e2 = 0; e2 < 4; ++e2)
                ps += sp(acc[mt][e2] + bv[e2]) * wv[e2];
        }
        ps += __shfl_xor(ps, 16);
        ps += __shfl_xor(ps, 32);   // full 128-row sum; all lanes hold psi[j]

        float cost = Ui[0] * ya.x + Ui[1] * ya.y + Ui[2] * ya.z + Ui[3] * ya.w +
                     Ui[4] * yb.x + Ui[5] * yb.y + Ui[6] * yb.z + Ui[7] * yb.w;
        const float slk = cost - ps - bout0;

        // ---- online LSE within the 16-lane group (16 distinct j, each once) ----
        float t = slk;
#pragma unroll
        for (int d = 1; d <= 8; d <<= 1) t = fmaxf(t, __shfl_xor(t, d));
        const float nm = fmaxf(m_run, t);
        float e = __expf((slk - nm) * INV_EPS);
#pragma unroll
        for (int d = 1; d <= 8; d <<= 1) e += __shfl_xor(e, d);
        s_run = s_run * __expf((m_run - nm) * INV_EPS) + e;
        m_run = nm;
    }

    // ---- cross-wave combine ----
    if (lane == 0) {
        ((float*)(smem + OFF_LSE))[wid]     = m_run;
        ((float*)(smem + OFF_LSE))[8 + wid] = s_run;
    }
    __syncthreads();
    if (tid == 0) {
        const float* lm = (const float*)(smem + OFF_LSE);
        float M = -INFINITY;
#pragma unroll
        for (int w = 0; w < NW; ++w) M = fmaxf(M, lm[w]);
        float S = 0.0f;
#pragma unroll
        for (int w = 0; w < NW; ++w) S += lm[8 + w] * __expf((lm[w] - M) * INV_EPS);
        outg[i] = EPS_F * (logf(S) - logf((float)NPTS)) + M;
    }
}

extern "C" void kernel_launch(void* const* d_in, const int* in_sizes, int n_in,
                              void* d_out, int out_size, void* d_ws, size_t ws_size,
                              hipStream_t stream) {
    const float* X    = (const float*)d_in[0];
    const float* U    = (const float*)d_in[1];
    const float* Y    = (const float*)d_in[2];
    const float* W0   = (const float*)d_in[3];
    const float* b0   = (const float*)d_in[4];
    const float* W1   = (const float*)d_in[5];
    const float* b1   = (const float*)d_in[6];
    const float* W2   = (const float*)d_in[7];
    const float* b2   = (const float*)d_in[8];
    const float* Wout = (const float*)d_in[9];
    const float* bout = (const float*)d_in[10];
    float* out = (float*)d_out;

    const size_t need_ws = (size_t)2 * NPTS * HID * sizeof(float);  // 1 MiB
    if (ws_size >= need_ws) {
        float* hX  = (float*)d_ws;
        float* hYP = hX + NPTS * HID;
        hipLaunchKernelGGL(eotqr_pre, dim3(NPTS), dim3(HID), 0, stream, X, Y, W0, b0, hX, hYP);
        (void)hipFuncSetAttribute((const void*)eotqr_mfma<true>,
                                  hipFuncAttributeMaxDynamicSharedMemorySize, LDS_BYTES);
        hipLaunchKernelGGL(eotqr_mfma<true>, dim3(NPTS), dim3(NTH), LDS_BYTES, stream,
                           X, U, Y, W0, b0, W1, b1, W2, b2, Wout, bout, hX, hYP, out);
    } else {
        (void)hipFuncSetAttribute((const void*)eotqr_mfma<false>,
                                  hipFuncAttributeMaxDynamicSharedMemorySize, LDS_BYTES);
        hipLaunchKernelGGL(eotqr_mfma<false>, dim3(NPTS), dim3(NTH), LDS_BYTES, stream,
                           X, U, Y, W0, b0, W1, b1, W2, b2, Wout, bout,
                           (const float*)nullptr, (const float*)nullptr, out);
    }
}

// Round 9
// 400.909 us; speedup vs baseline: 4.5587x; 4.5587x over previous
//
#include <hip/hip_runtime.h>

// EntropicOTQuantileRegression — R9: R8's barrier-free per-wave strips, with
// the spill killed. (1) STATIC __shared__ (153KB): compiler finally SEES the
// LDS (LDS_Block_Size was 0 in R3-R8 -> it budgeted registers for impossible
// occupancy). (2) per-mt reorder fence in GEMM bounds hoisted ds_read
// transients to <=8 loads (32 VGPR) so worst-case live state fits 128.

#define NPTS 1024
#define FDIM 64
#define RDIM 8
#define HID  128
#define NTH  512
#define NW   8
#define JW   16
#define NPASS (NPTS / (NW * JW))   // 8
#define EPS_F 0.1f
#define INV_EPS 10.0f

typedef __attribute__((ext_vector_type(8))) short short8;   // 8 bf16
typedef __attribute__((ext_vector_type(4))) float f32x4;

// LDS byte offsets
#define OFF_WF1  0         // 65536: W1 frags [mt8][ks4][hi/lo][lane*16]
#define OFF_WF2  65536     // 65536: W2 frags (rho-permuted k rows)
#define OFF_STG  131072    // 16384: init staging chunk (32 rows x 128 f32)
#define OFF_HXI  147456    // 512
#define OFF_B1   147968    // 512
#define OFF_B2   148480    // 512
#define OFF_WOUT 148992    // 512
#define OFF_W0R  149504    // 4096 (fallback only)
#define OFF_LSE  153600    // 64
#define LDS_BYTES 153664   // < 163840

__device__ __forceinline__ float sp(float x) {
    return fmaxf(x, 0.0f) + __logf(1.0f + __expf(-fabsf(x)));
}
__device__ __forceinline__ unsigned bcu(float x) { return __builtin_bit_cast(unsigned, x); }
__device__ __forceinline__ float bcf(unsigned x) { return __builtin_bit_cast(float, x); }
__device__ __forceinline__ unsigned short bf16rne(float x) {
    unsigned u = bcu(x);
    return (unsigned short)((u + 0x7FFFu + ((u >> 16) & 1u)) >> 16);
}
__device__ __forceinline__ void hilo(float x, unsigned short& h, unsigned short& l) {
    unsigned u = bcu(x);
    unsigned hb = (u + 0x7FFFu + ((u >> 16) & 1u)) & 0xFFFF0000u;
    h = (unsigned short)(hb >> 16);
    l = bf16rne(x - bcf(hb));
}

// pre-kernel: hX[n][c] natural; hY in the coalesced frag-read layout:
// hYP[(n>>4)*2048 + (c>>2)*64 + (n&15)*4 + (c&3)]
__global__ void eotqr_pre(const float* __restrict__ Xg, const float* __restrict__ Yg,
                          const float* __restrict__ W0g, const float* __restrict__ b0g,
                          float* __restrict__ hX, float* __restrict__ hYP) {
    const int n = blockIdx.x, c = threadIdx.x;
    float a = b0g[c];
    for (int f = 0; f < FDIM; ++f) a += Xg[n * FDIM + f] * W0g[f * HID + c];
    hX[n * HID + c] = a;
    float b = 0.0f;
#pragma unroll
    for (int r = 0; r < RDIM; ++r) b += Yg[n * RDIM + r] * W0g[(FDIM + r) * HID + c];
    hYP[(n >> 4) * 2048 + (c >> 2) * 64 + (n & 15) * 4 + (c & 3)] = b;
}

// Stage one layer's W into frag-linear LDS. Chunk r = raw rows [32r,32r+32)
// == frags ks=r. Wave w builds mt=w. IS_W2 applies rho (layer1-C == layer2-B).
#define STAGE_LAYER(WSRC, WFBASE, IS_W2)                                      \
    for (int r = 0; r < 4; ++r) {                                             \
        __syncthreads();                                                      \
        for (int e4 = tid; e4 < 1024; e4 += NTH)                              \
            ((float4*)(smem + OFF_STG))[e4] =                                 \
                ((const float4*)((WSRC) + r * 32 * HID))[e4];                 \
        __syncthreads();                                                      \
        {                                                                     \
            const float* stg = (const float*)(smem + OFF_STG);                \
            const int mt = wid;                                               \
            union { unsigned short u[8]; short8 v; } ph, pl;                  \
            _Pragma("unroll")                                                 \
            for (int e = 0; e < 8; ++e) {                                     \
                const int kloc = (IS_W2) ? ((e >= 4) * 16 + g * 4 + (e & 3))  \
                                         : (g * 8 + e);                       \
                hilo(stg[kloc * HID + mt * 16 + (lane & 15)], ph.u[e], pl.u[e]); \
            }                                                                 \
            *(short8*)(smem + (WFBASE) + ((mt * 4 + r) * 2 + 0) * 1024 + lane * 16) = ph.v; \
            *(short8*)(smem + (WFBASE) + ((mt * 4 + r) * 2 + 1) * 1024 + lane * 16) = pl.v; \
        }                                                                     \
    }

// Per-mt reorder fence bounds the scheduler's hoisted ds_read transients.
#define GEMM_LAYER(WFBASE)                                                    \
    _Pragma("unroll")                                                         \
    for (int mt = 0; mt < 8; ++mt) acc[mt] = f32x4{0.f, 0.f, 0.f, 0.f};       \
    _Pragma("unroll")                                                         \
    for (int mt = 0; mt < 8; ++mt) {                                          \
        _Pragma("unroll")                                                     \
        for (int ks = 0; ks < 4; ++ks) {                                      \
            const short8 ah = *(const short8*)(smem + (WFBASE) + ((mt * 4 + ks) * 2 + 0) * 1024 + lane * 16); \
            const short8 al = *(const short8*)(smem + (WFBASE) + ((mt * 4 + ks) * 2 + 1) * 1024 + lane * 16); \
            acc[mt] = __builtin_amdgcn_mfma_f32_16x16x32_bf16(ah, bh[ks], acc[mt], 0, 0, 0); \
            acc[mt] = __builtin_amdgcn_mfma_f32_16x16x32_bf16(al, bh[ks], acc[mt], 0, 0, 0); \
            acc[mt] = __builtin_amdgcn_mfma_f32_16x16x32_bf16(ah, bl[ks], acc[mt], 0, 0, 0); \
        }                                                                     \
        asm volatile("" ::: "memory");                                        \
    }

template <bool USE_WS>
__global__
__attribute__((amdgpu_flat_work_group_size(NTH, NTH)))
__attribute__((amdgpu_waves_per_eu(1, 2)))
void eotqr_mfma(const float* __restrict__ Xg, const float* __restrict__ Ug,
                const float* __restrict__ Yg, const float* __restrict__ W0g,
                const float* __restrict__ b0g, const float* __restrict__ W1g,
                const float* __restrict__ b1g, const float* __restrict__ W2g,
                const float* __restrict__ b2g, const float* __restrict__ Woutg,
                const float* __restrict__ boutg, const float* __restrict__ hXg,
                const float* __restrict__ hYg, float* __restrict__ outg) {
    __shared__ __align__(16) char smem[LDS_BYTES];   // STATIC: compiler sees it
    const int tid  = threadIdx.x;
    const int i    = blockIdx.x;
    const int lane = tid & 63;
    const int wid  = tid >> 6;
    const int g    = lane >> 4;

    // ---- init: small tables ----
    if (tid < HID) {
        ((float*)(smem + OFF_B1))[tid]   = b1g[tid];
        ((float*)(smem + OFF_B2))[tid]   = b2g[tid];
        ((float*)(smem + OFF_WOUT))[tid] = Woutg[tid];
        float a;
        if (USE_WS) {
            a = hXg[i * HID + tid];
        } else {
            a = b0g[tid];
            for (int f = 0; f < FDIM; ++f) a += Xg[i * FDIM + f] * W0g[f * HID + tid];
        }
        ((float*)(smem + OFF_HXI))[tid] = a;
    }
    if (!USE_WS)
        for (int e = tid; e < RDIM * HID; e += NTH)
            ((float*)(smem + OFF_W0R))[e] = W0g[FDIM * HID + e];

    // ---- stage W frags (the only barriers besides the final combine) ----
    STAGE_LAYER(W1g, OFF_WF1, 0)
    STAGE_LAYER(W2g, OFF_WF2, 1)
    __syncthreads();

    const float bout0 = boutg[0];
    float Ui[RDIM];
#pragma unroll
    for (int r = 0; r < RDIM; ++r) Ui[r] = Ug[i * RDIM + r];

    float m_run = -INFINITY, s_run = 0.0f;

#pragma unroll 1
    for (int p = 0; p < NPASS; ++p) {
        const int jme = p * (NW * JW) + wid * JW + (lane & 15);  // this lane's j
        // Y row (for fallback hY and for the cost dot)
        const float4 ya = *(const float4*)(Yg + jme * RDIM);
        const float4 yb = *(const float4*)(Yg + jme * RDIM + 4);

        // ---- layer 0: B1 frags in registers ----
        short8 bh[4], bl[4];
#pragma unroll
        for (int ks = 0; ks < 4; ++ks) {
            float s[8];
            if (USE_WS) {
                const float* hb = hYg + (size_t)(p * NW + wid) * 2048 + (lane & 15) * 4;
                const float4 q0 = *(const float4*)(hb + (8 * ks + 2 * g + 0) * 64);
                const float4 q1 = *(const float4*)(hb + (8 * ks + 2 * g + 1) * 64);
                s[0] = q0.x; s[1] = q0.y; s[2] = q0.z; s[3] = q0.w;
                s[4] = q1.x; s[5] = q1.y; s[6] = q1.z; s[7] = q1.w;
            } else {
                const float* w0r = (const float*)(smem + OFF_W0R);
                const float yv[8] = {ya.x, ya.y, ya.z, ya.w, yb.x, yb.y, yb.z, yb.w};
#pragma unroll
                for (int e = 0; e < 8; ++e) {
                    float b = 0.0f;
#pragma unroll
                    for (int r = 0; r < RDIM; ++r)
                        b += yv[r] * w0r[r * HID + 32 * ks + 8 * g + e];
                    s[e] = b;
                }
            }
            const float4 hx0 = *(const float4*)(smem + OFF_HXI + (32 * ks + 8 * g) * 4);
            const float4 hx1 = *(const float4*)(smem + OFF_HXI + (32 * ks + 8 * g) * 4 + 16);
            s[0] += hx0.x; s[1] += hx0.y; s[2] += hx0.z; s[3] += hx0.w;
            s[4] += hx1.x; s[5] += hx1.y; s[6] += hx1.z; s[7] += hx1.w;
            union { unsigned short u[8]; short8 v; } ph, pl;
#pragma unroll
            for (int e = 0; e < 8; ++e) hilo(sp(s[e]), ph.u[e], pl.u[e]);
            bh[ks] = ph.v; bl[ks] = pl.v;
        }

        f32x4 acc[8];
        // ---- layer 1 ----
        GEMM_LAYER(OFF_WF1)

        // ---- epi1: C-frags -> B2 frags in-lane (rho handled at W2 staging) ----
#pragma unroll
        for (int ks = 0; ks < 4; ++ks) {
            union { unsigned short u[8]; short8 v; } ph, pl;
#pragma unroll
            for (int b = 0; b < 2; ++b) {
                const int mt = 2 * ks + b;
                const float4 bias = *(const float4*)(smem + OFF_B1 + (mt * 16 + 4 * g) * 4);
                const float bv[4] = {bias.x, bias.y, bias.z, bias.w};
#pragma unroll
                for (int e2 = 0; e2 < 4; ++e2)
                    hilo(sp(acc[mt][e2] + bv[e2]), ph.u[b * 4 + e2], pl.u[b * 4 + e2]);
            }
            bh[ks] = ph.v; bl[ks] = pl.v;
        }

        // ---- layer 2 ----
        GEMM_LAYER(OFF_WF2)

        // ---- epi2: psi partial over this lane's rows ----
        float ps = 0.0f;
#pragma unroll
        for (int mt = 0; mt < 8; ++mt) {
            const float4 b2v = *(const float4*)(smem + OFF_B2 + (mt * 16 + 4 * g) * 4);
            const float4 wov = *(const float4*)(smem + OFF_WOUT + (mt * 16 + 4 * g) * 4);
            const float bv[4] = {b2v.x, b2v.y, b2v.z, b2v.w};
            const float wv[4] = {wov.x, wov.y, wov.z, wov.w};
#pragma unroll
            for (int e2 = 0; e2 < 4; ++e2)
                ps += sp(acc[mt][e2] + bv[e2]) * wv[e2];
        }
        ps += __shfl_xor(ps, 16);
        ps += __shfl_xor(ps, 32);   // full 128-row sum; all lanes hold psi[j]

        float cost = Ui[0] * ya.x + Ui[1] * ya.y + Ui[2] * ya.z + Ui[3] * ya.w +
                     Ui[4] * yb.x + Ui[5] * yb.y + Ui[6] * yb.z + Ui[7] * yb.w;
        const float slk = cost - ps - bout0;

        // ---- online LSE within the 16-lane group (16 distinct j, each once) ----
        float t = slk;
#pragma unroll
        for (int d = 1; d <= 8; d <<= 1) t = fmaxf(t, __shfl_xor(t, d));
        const float nm = fmaxf(m_run, t);
        float e = __expf((slk - nm) * INV_EPS);
#pragma unroll
        for (int d = 1; d <= 8; d <<= 1) e += __shfl_xor(e, d);
        s_run = s_run * __expf((m_run - nm) * INV_EPS) + e;
        m_run = nm;
    }

    // ---- cross-wave combine ----
    if (lane == 0) {
        ((float*)(smem + OFF_LSE))[wid]     = m_run;
        ((float*)(smem + OFF_LSE))[8 + wid] = s_run;
    }
    __syncthreads();
    if (tid == 0) {
        const float* lm = (const float*)(smem + OFF_LSE);
        float M = -INFINITY;
#pragma unroll
        for (int w = 0; w < NW; ++w) M = fmaxf(M, lm[w]);
        float S = 0.0f;
#pragma unroll
        for (int w = 0; w < NW; ++w) S += lm[8 + w] * __expf((lm[w] - M) * INV_EPS);
        outg[i] = EPS_F * (logf(S) - logf((float)NPTS)) + M;
    }
}

extern "C" void kernel_launch(void* const* d_in, const int* in_sizes, int n_in,
                              void* d_out, int out_size, void* d_ws, size_t ws_size,
                              hipStream_t stream) {
    const float* X    = (const float*)d_in[0];
    const float* U    = (const float*)d_in[1];
    const float* Y    = (const float*)d_in[2];
    const float* W0   = (const float*)d_in[3];
    const float* b0   = (const float*)d_in[4];
    const float* W1   = (const float*)d_in[5];
    const float* b1   = (const float*)d_in[6];
    const float* W2   = (const float*)d_in[7];
    const float* b2   = (const float*)d_in[8];
    const float* Wout = (const float*)d_in[9];
    const float* bout = (const float*)d_in[10];
    float* out = (float*)d_out;

    const size_t need_ws = (size_t)2 * NPTS * HID * sizeof(float);  // 1 MiB
    if (ws_size >= need_ws) {
        float* hX  = (float*)d_ws;
        float* hYP = hX + NPTS * HID;
        hipLaunchKernelGGL(eotqr_pre, dim3(NPTS), dim3(HID), 0, stream, X, Y, W0, b0, hX, hYP);
        hipLaunchKernelGGL(eotqr_mfma<true>, dim3(NPTS), dim3(NTH), 0, stream,
                           X, U, Y, W0, b0, W1, b1, W2, b2, Wout, bout, hX, hYP, out);
    } else {
        hipLaunchKernelGGL(eotqr_mfma<false>, dim3(NPTS), dim3(NTH), 0, stream,
                           X, U, Y, W0, b0, W1, b1, W2, b2, Wout, bout,
                           (const float*)nullptr, (const float*)nullptr, out);
    }
}

// Round 10
// 346.732 us; speedup vs baseline: 5.2709x; 1.1563x over previous
//
#include <hip/hip_runtime.h>
#include <hip/hip_bf16.h>

// EntropicOTQuantileRegression — R10. Two independent levers on R9:
//  (1) VALU: hilo via HW v_cvt_pk_bf16_f32 (__float2bfloat16) instead of
//      manual RNE bit-arith (~12 -> ~3 inst/value). lo-term makes hi's
//      rounding mode irrelevant (residual = Wlo*Hlo either way).
//  (2) LDS: JW 16->32 (two j-groups per wave share each A-frag read) ->
//      W-fragment LDS traffic halves. acc x2 expected in AGPRs (unified
//      file); decisive spill counter = WRITE_SIZE.

#define NPTS 1024
#define FDIM 64
#define RDIM 8
#define HID  128
#define NTH  512
#define NW   8
#define JW   32
#define NPASS (NPTS / (NW * JW))   // 4
#define EPS_F 0.1f
#define INV_EPS 10.0f

typedef __attribute__((ext_vector_type(8))) short short8;   // 8 bf16
typedef __attribute__((ext_vector_type(4))) float f32x4;

// LDS byte offsets
#define OFF_WF1  0         // 65536: W1 frags [mt8][ks4][hi/lo][lane*16]
#define OFF_WF2  65536     // 65536: W2 frags (rho-permuted k rows)
#define OFF_STG  131072    // 16384: init staging chunk (32 rows x 128 f32)
#define OFF_HXI  147456    // 512
#define OFF_B1   147968    // 512
#define OFF_B2   148480    // 512
#define OFF_WOUT 148992    // 512
#define OFF_W0R  149504    // 4096 (fallback only)
#define OFF_LSE  153600    // 64
#define LDS_BYTES 153664   // < 163840

__device__ __forceinline__ float sp(float x) {
    return fmaxf(x, 0.0f) + __logf(1.0f + __expf(-fabsf(x)));
}
__device__ __forceinline__ float bcf(unsigned x) { return __builtin_bit_cast(float, x); }
__device__ __forceinline__ unsigned short bf16c(float x) {
    return __builtin_bit_cast(unsigned short, __float2bfloat16(x));
}
// hi/lo split via HW cvt: hi = bf16(x), lo = bf16(x - hi).
__device__ __forceinline__ void hilo(float x, unsigned short& h, unsigned short& l) {
    h = bf16c(x);
    l = bf16c(x - bcf(((unsigned)h) << 16));
}

// pre-kernel: hX[n][c] natural; hY in the coalesced frag-read layout:
// hYP[(n>>4)*2048 + (c>>2)*64 + (n&15)*4 + (c&3)]
__global__ void eotqr_pre(const float* __restrict__ Xg, const float* __restrict__ Yg,
                          const float* __restrict__ W0g, const float* __restrict__ b0g,
                          float* __restrict__ hX, float* __restrict__ hYP) {
    const int n = blockIdx.x, c = threadIdx.x;
    float a = b0g[c];
    for (int f = 0; f < FDIM; ++f) a += Xg[n * FDIM + f] * W0g[f * HID + c];
    hX[n * HID + c] = a;
    float b = 0.0f;
#pragma unroll
    for (int r = 0; r < RDIM; ++r) b += Yg[n * RDIM + r] * W0g[(FDIM + r) * HID + c];
    hYP[(n >> 4) * 2048 + (c >> 2) * 64 + (n & 15) * 4 + (c & 3)] = b;
}

// Stage one layer's W into frag-linear LDS. Chunk r = raw rows [32r,32r+32)
// == frags ks=r. Wave w builds mt=w. IS_W2 applies rho (layer1-C == layer2-B).
#define STAGE_LAYER(WSRC, WFBASE, IS_W2)                                      \
    for (int r = 0; r < 4; ++r) {                                             \
        __syncthreads();                                                      \
        for (int e4 = tid; e4 < 1024; e4 += NTH)                              \
            ((float4*)(smem + OFF_STG))[e4] =                                 \
                ((const float4*)((WSRC) + r * 32 * HID))[e4];                 \
        __syncthreads();                                                      \
        {                                                                     \
            const float* stg = (const float*)(smem + OFF_STG);                \
            const int mt = wid;                                               \
            union { unsigned short u[8]; short8 v; } ph, pl;                  \
            _Pragma("unroll")                                                 \
            for (int e = 0; e < 8; ++e) {                                     \
                const int kloc = (IS_W2) ? ((e >= 4) * 16 + g * 4 + (e & 3))  \
                                         : (g * 8 + e);                       \
                hilo(stg[kloc * HID + mt * 16 + (lane & 15)], ph.u[e], pl.u[e]); \
            }                                                                 \
            *(short8*)(smem + (WFBASE) + ((mt * 4 + r) * 2 + 0) * 1024 + lane * 16) = ph.v; \
            *(short8*)(smem + (WFBASE) + ((mt * 4 + r) * 2 + 1) * 1024 + lane * 16) = pl.v; \
        }                                                                     \
    }

// Two j-groups share each A-frag read: 2 ds_read_b128 feed 6 MFMAs.
#define GEMM_LAYER(WFBASE)                                                    \
    _Pragma("unroll")                                                         \
    for (int mt = 0; mt < 8; ++mt) {                                          \
        acc0[mt] = f32x4{0.f, 0.f, 0.f, 0.f};                                 \
        acc1[mt] = f32x4{0.f, 0.f, 0.f, 0.f};                                 \
    }                                                                         \
    _Pragma("unroll")                                                         \
    for (int mt = 0; mt < 8; ++mt) {                                          \
        _Pragma("unroll")                                                     \
        for (int ks = 0; ks < 4; ++ks) {                                      \
            const short8 ah = *(const short8*)(smem + (WFBASE) + ((mt * 4 + ks) * 2 + 0) * 1024 + lane * 16); \
            const short8 al = *(const short8*)(smem + (WFBASE) + ((mt * 4 + ks) * 2 + 1) * 1024 + lane * 16); \
            acc0[mt] = __builtin_amdgcn_mfma_f32_16x16x32_bf16(ah, bh0[ks], acc0[mt], 0, 0, 0); \
            acc0[mt] = __builtin_amdgcn_mfma_f32_16x16x32_bf16(al, bh0[ks], acc0[mt], 0, 0, 0); \
            acc0[mt] = __builtin_amdgcn_mfma_f32_16x16x32_bf16(ah, bl0[ks], acc0[mt], 0, 0, 0); \
            acc1[mt] = __builtin_amdgcn_mfma_f32_16x16x32_bf16(ah, bh1[ks], acc1[mt], 0, 0, 0); \
            acc1[mt] = __builtin_amdgcn_mfma_f32_16x16x32_bf16(al, bh1[ks], acc1[mt], 0, 0, 0); \
            acc1[mt] = __builtin_amdgcn_mfma_f32_16x16x32_bf16(ah, bl1[ks], acc1[mt], 0, 0, 0); \
        }                                                                     \
        asm volatile("" ::: "memory");                                        \
    }

template <bool USE_WS>
__global__
__attribute__((amdgpu_flat_work_group_size(NTH, NTH)))
__attribute__((amdgpu_waves_per_eu(1, 2)))
void eotqr_mfma(const float* __restrict__ Xg, const float* __restrict__ Ug,
                const float* __restrict__ Yg, const float* __restrict__ W0g,
                const float* __restrict__ b0g, const float* __restrict__ W1g,
                const float* __restrict__ b1g, const float* __restrict__ W2g,
                const float* __restrict__ b2g, const float* __restrict__ Woutg,
                const float* __restrict__ boutg, const float* __restrict__ hXg,
                const float* __restrict__ hYg, float* __restrict__ outg) {
    __shared__ __align__(16) char smem[LDS_BYTES];
    const int tid  = threadIdx.x;
    const int i    = blockIdx.x;
    const int lane = tid & 63;
    const int wid  = tid >> 6;
    const int g    = lane >> 4;

    // ---- init: small tables ----
    if (tid < HID) {
        ((float*)(smem + OFF_B1))[tid]   = b1g[tid];
        ((float*)(smem + OFF_B2))[tid]   = b2g[tid];
        ((float*)(smem + OFF_WOUT))[tid] = Woutg[tid];
        float a;
        if (USE_WS) {
            a = hXg[i * HID + tid];
        } else {
            a = b0g[tid];
            for (int f = 0; f < FDIM; ++f) a += Xg[i * FDIM + f] * W0g[f * HID + tid];
        }
        ((float*)(smem + OFF_HXI))[tid] = a;
    }
    if (!USE_WS)
        for (int e = tid; e < RDIM * HID; e += NTH)
            ((float*)(smem + OFF_W0R))[e] = W0g[FDIM * HID + e];

    // ---- stage W frags ----
    STAGE_LAYER(W1g, OFF_WF1, 0)
    STAGE_LAYER(W2g, OFF_WF2, 1)
    __syncthreads();

    const float bout0 = boutg[0];
    float Ui[RDIM];
#pragma unroll
    for (int r = 0; r < RDIM; ++r) Ui[r] = Ug[i * RDIM + r];

    float m_run = -INFINITY, s_run = 0.0f;

#pragma unroll 1
    for (int p = 0; p < NPASS; ++p) {
        const int jme0 = p * (NW * JW) + wid * JW + (lane & 15);
        const int jme1 = jme0 + 16;
        const float4 ya0 = *(const float4*)(Yg + jme0 * RDIM);
        const float4 yb0 = *(const float4*)(Yg + jme0 * RDIM + 4);
        const float4 ya1 = *(const float4*)(Yg + jme1 * RDIM);
        const float4 yb1 = *(const float4*)(Yg + jme1 * RDIM + 4);

        // ---- layer 0: two B1 frag sets in registers ----
        short8 bh0[4], bl0[4], bh1[4], bl1[4];
#pragma unroll
        for (int ks = 0; ks < 4; ++ks) {
            float s0[8], s1[8];
            if (USE_WS) {
                const int gi0 = (p * NW + wid) * 2;
                const float* hb0 = hYg + (size_t)gi0 * 2048 + (lane & 15) * 4;
                const float* hb1 = hb0 + 2048;
                const float4 q00 = *(const float4*)(hb0 + (8 * ks + 2 * g + 0) * 64);
                const float4 q01 = *(const float4*)(hb0 + (8 * ks + 2 * g + 1) * 64);
                const float4 q10 = *(const float4*)(hb1 + (8 * ks + 2 * g + 0) * 64);
                const float4 q11 = *(const float4*)(hb1 + (8 * ks + 2 * g + 1) * 64);
                s0[0] = q00.x; s0[1] = q00.y; s0[2] = q00.z; s0[3] = q00.w;
                s0[4] = q01.x; s0[5] = q01.y; s0[6] = q01.z; s0[7] = q01.w;
                s1[0] = q10.x; s1[1] = q10.y; s1[2] = q10.z; s1[3] = q10.w;
                s1[4] = q11.x; s1[5] = q11.y; s1[6] = q11.z; s1[7] = q11.w;
            } else {
                const float* w0r = (const float*)(smem + OFF_W0R);
                const float yv0[8] = {ya0.x, ya0.y, ya0.z, ya0.w, yb0.x, yb0.y, yb0.z, yb0.w};
                const float yv1[8] = {ya1.x, ya1.y, ya1.z, ya1.w, yb1.x, yb1.y, yb1.z, yb1.w};
#pragma unroll
                for (int e = 0; e < 8; ++e) {
                    float b0a = 0.0f, b1a = 0.0f;
#pragma unroll
                    for (int r = 0; r < RDIM; ++r) {
                        const float w = w0r[r * HID + 32 * ks + 8 * g + e];
                        b0a += yv0[r] * w;
                        b1a += yv1[r] * w;
                    }
                    s0[e] = b0a; s1[e] = b1a;
                }
            }
            const float4 hx0 = *(const float4*)(smem + OFF_HXI + (32 * ks + 8 * g) * 4);
            const float4 hx1 = *(const float4*)(smem + OFF_HXI + (32 * ks + 8 * g) * 4 + 16);
            const float hxv[8] = {hx0.x, hx0.y, hx0.z, hx0.w, hx1.x, hx1.y, hx1.z, hx1.w};
            union { unsigned short u[8]; short8 v; } p0h, p0l, p1h, p1l;
#pragma unroll
            for (int e = 0; e < 8; ++e) {
                hilo(sp(s0[e] + hxv[e]), p0h.u[e], p0l.u[e]);
                hilo(sp(s1[e] + hxv[e]), p1h.u[e], p1l.u[e]);
            }
            bh0[ks] = p0h.v; bl0[ks] = p0l.v;
            bh1[ks] = p1h.v; bl1[ks] = p1l.v;
        }

        f32x4 acc0[8], acc1[8];
        // ---- layer 1 ----
        GEMM_LAYER(OFF_WF1)

        // ---- epi1: C-frags -> B2 frags in-lane (rho at W2 staging) ----
#pragma unroll
        for (int ks = 0; ks < 4; ++ks) {
            union { unsigned short u[8]; short8 v; } p0h, p0l, p1h, p1l;
#pragma unroll
            for (int b = 0; b < 2; ++b) {
                const int mt = 2 * ks + b;
                const float4 bias = *(const float4*)(smem + OFF_B1 + (mt * 16 + 4 * g) * 4);
                const float bv[4] = {bias.x, bias.y, bias.z, bias.w};
#pragma unroll
                for (int e2 = 0; e2 < 4; ++e2) {
                    hilo(sp(acc0[mt][e2] + bv[e2]), p0h.u[b * 4 + e2], p0l.u[b * 4 + e2]);
                    hilo(sp(acc1[mt][e2] + bv[e2]), p1h.u[b * 4 + e2], p1l.u[b * 4 + e2]);
                }
            }
            bh0[ks] = p0h.v; bl0[ks] = p0l.v;
            bh1[ks] = p1h.v; bl1[ks] = p1l.v;
        }

        // ---- layer 2 ----
        GEMM_LAYER(OFF_WF2)

        // ---- epi2: psi partials ----
        float ps0 = 0.0f, ps1 = 0.0f;
#pragma unroll
        for (int mt = 0; mt < 8; ++mt) {
            const float4 b2v = *(const float4*)(smem + OFF_B2 + (mt * 16 + 4 * g) * 4);
            const float4 wov = *(const float4*)(smem + OFF_WOUT + (mt * 16 + 4 * g) * 4);
            const float bv[4] = {b2v.x, b2v.y, b2v.z, b2v.w};
            const float wv[4] = {wov.x, wov.y, wov.z, wov.w};
#pragma unroll
            for (int e2 = 0; e2 < 4; ++e2) {
                ps0 += sp(acc0[mt][e2] + bv[e2]) * wv[e2];
                ps1 += sp(acc1[mt][e2] + bv[e2]) * wv[e2];
            }
        }
        ps0 += __shfl_xor(ps0, 16); ps0 += __shfl_xor(ps0, 32);
        ps1 += __shfl_xor(ps1, 16); ps1 += __shfl_xor(ps1, 32);

        const float cost0 = Ui[0]*ya0.x + Ui[1]*ya0.y + Ui[2]*ya0.z + Ui[3]*ya0.w +
                            Ui[4]*yb0.x + Ui[5]*yb0.y + Ui[6]*yb0.z + Ui[7]*yb0.w;
        const float cost1 = Ui[0]*ya1.x + Ui[1]*ya1.y + Ui[2]*ya1.z + Ui[3]*ya1.w +
                            Ui[4]*yb1.x + Ui[5]*yb1.y + Ui[6]*yb1.z + Ui[7]*yb1.w;
        const float slk0 = cost0 - ps0 - bout0;
        const float slk1 = cost1 - ps1 - bout0;

        // ---- online LSE within the 16-lane group (32 distinct j) ----
        float t = fmaxf(slk0, slk1);
#pragma unroll
        for (int d = 1; d <= 8; d <<= 1) t = fmaxf(t, __shfl_xor(t, d));
        const float nm = fmaxf(m_run, t);
        float e = __expf((slk0 - nm) * INV_EPS) + __expf((slk1 - nm) * INV_EPS);
#pragma unroll
        for (int d = 1; d <= 8; d <<= 1) e += __shfl_xor(e, d);
        s_run = s_run * __expf((m_run - nm) * INV_EPS) + e;
        m_run = nm;
    }

    // ---- cross-wave combine ----
    if (lane == 0) {
        ((float*)(smem + OFF_LSE))[wid]     = m_run;
        ((float*)(smem + OFF_LSE))[8 + wid] = s_run;
    }
    __syncthreads();
    if (tid == 0) {
        const float* lm = (const float*)(smem + OFF_LSE);
        float M = -INFINITY;
#pragma unroll
        for (int w = 0; w < NW; ++w) M = fmaxf(M, lm[w]);
        float S = 0.0f;
#pragma unroll
        for (int w = 0; w < NW; ++w) S += lm[8 + w] * __expf((lm[w] - M) * INV_EPS);
        outg[i] = EPS_F * (logf(S) - logf((float)NPTS)) + M;
    }
}

extern "C" void kernel_launch(void* const* d_in, const int* in_sizes, int n_in,
                              void* d_out, int out_size, void* d_ws, size_t ws_size,
                              hipStream_t stream) {
    const float* X    = (const float*)d_in[0];
    const float* U    = (const float*)d_in[1];
    const float* Y    = (const float*)d_in[2];
    const float* W0   = (const float*)d_in[3];
    const float* b0   = (const float*)d_in[4];
    const float* W1   = (const float*)d_in[5];
    const float* b1   = (const float*)d_in[6];
    const float* W2   = (const float*)d_in[7];
    const float* b2   = (const float*)d_in[8];
    const float* Wout = (const float*)d_in[9];
    const float* bout = (const float*)d_in[10];
    float* out = (float*)d_out;

    const size_t need_ws = (size_t)2 * NPTS * HID * sizeof(float);  // 1 MiB
    if (ws_size >= need_ws) {
        float* hX  = (float*)d_ws;
        float* hYP = hX + NPTS * HID;
        hipLaunchKernelGGL(eotqr_pre, dim3(NPTS), dim3(HID), 0, stream, X, Y, W0, b0, hX, hYP);
        hipLaunchKernelGGL(eotqr_mfma<true>, dim3(NPTS), dim3(NTH), 0, stream,
                           X, U, Y, W0, b0, W1, b1, W2, b2, Wout, bout, hX, hYP, out);
    } else {
        hipLaunchKernelGGL(eotqr_mfma<false>, dim3(NPTS), dim3(NTH), 0, stream,
                           X, U, Y, W0, b0, W1, b1, W2, b2, Wout, bout,
                           (const float*)nullptr, (const float*)nullptr, out);
    }
}

// Round 11
// 340.936 us; speedup vs baseline: 5.3606x; 1.0170x over previous
//
#include <hip/hip_runtime.h>
#include <hip/hip_bf16.h>

// EntropicOTQuantileRegression — R11. Single variable vs R10: occupancy.
// NTH 512->1024 (16 waves/block, 4 waves/SIMD, still 1 block/CU) and JW
// back to 16 so per-thread regs (~100) fit the 128/wave budget 16 waves/CU
// needs. R10 counters: VALU busy 280us of 395us wall at 2 waves/SIMD ->
// the 29% idle is un-hidden latency; 4 waves/SIMD should saturate VALU.

#define NPTS 1024
#define FDIM 64
#define RDIM 8
#define HID  128
#define NTH  1024
#define NW   16
#define JW   16
#define NPASS (NPTS / (NW * JW))   // 4
#define EPS_F 0.1f
#define INV_EPS 10.0f

typedef __attribute__((ext_vector_type(8))) short short8;   // 8 bf16
typedef __attribute__((ext_vector_type(4))) float f32x4;

// LDS byte offsets
#define OFF_WF1  0         // 65536: W1 frags [mt8][ks4][hi/lo][lane*16]
#define OFF_WF2  65536     // 65536: W2 frags (rho-permuted k rows)
#define OFF_STG  131072    // 16384: init staging chunk (32 rows x 128 f32)
#define OFF_HXI  147456    // 512
#define OFF_B1   147968    // 512
#define OFF_B2   148480    // 512
#define OFF_WOUT 148992    // 512
#define OFF_W0R  149504    // 4096 (fallback only)
#define OFF_LSE  153600    // 128 (16 waves x {m,s})
#define LDS_BYTES 153728   // < 163840

__device__ __forceinline__ float sp(float x) {
    return fmaxf(x, 0.0f) + __logf(1.0f + __expf(-fabsf(x)));
}
__device__ __forceinline__ float bcf(unsigned x) { return __builtin_bit_cast(float, x); }
__device__ __forceinline__ unsigned short bf16c(float x) {
    return __builtin_bit_cast(unsigned short, __float2bfloat16(x));
}
// hi/lo split: hi = bf16(x), lo = bf16(x - hi).
__device__ __forceinline__ void hilo(float x, unsigned short& h, unsigned short& l) {
    h = bf16c(x);
    l = bf16c(x - bcf(((unsigned)h) << 16));
}

// pre-kernel: hX[n][c] natural; hY in the coalesced frag-read layout:
// hYP[(n>>4)*2048 + (c>>2)*64 + (n&15)*4 + (c&3)]
__global__ void eotqr_pre(const float* __restrict__ Xg, const float* __restrict__ Yg,
                          const float* __restrict__ W0g, const float* __restrict__ b0g,
                          float* __restrict__ hX, float* __restrict__ hYP) {
    const int n = blockIdx.x, c = threadIdx.x;
    float a = b0g[c];
    for (int f = 0; f < FDIM; ++f) a += Xg[n * FDIM + f] * W0g[f * HID + c];
    hX[n * HID + c] = a;
    float b = 0.0f;
#pragma unroll
    for (int r = 0; r < RDIM; ++r) b += Yg[n * RDIM + r] * W0g[(FDIM + r) * HID + c];
    hYP[(n >> 4) * 2048 + (c >> 2) * 64 + (n & 15) * 4 + (c & 3)] = b;
}

// Stage one layer's W into frag-linear LDS. Chunk r = raw rows [32r,32r+32)
// == frags ks=r. Waves 0..7 build mt=wid; waves 8..15 only help the copy.
#define STAGE_LAYER(WSRC, WFBASE, IS_W2)                                      \
    for (int r = 0; r < 4; ++r) {                                             \
        __syncthreads();                                                      \
        for (int e4 = tid; e4 < 1024; e4 += NTH)                              \
            ((float4*)(smem + OFF_STG))[e4] =                                 \
                ((const float4*)((WSRC) + r * 32 * HID))[e4];                 \
        __syncthreads();                                                      \
        if (wid < 8) {                                                        \
            const float* stg = (const float*)(smem + OFF_STG);                \
            const int mt = wid;                                               \
            union { unsigned short u[8]; short8 v; } ph, pl;                  \
            _Pragma("unroll")                                                 \
            for (int e = 0; e < 8; ++e) {                                     \
                const int kloc = (IS_W2) ? ((e >= 4) * 16 + g * 4 + (e & 3))  \
                                         : (g * 8 + e);                       \
                hilo(stg[kloc * HID + mt * 16 + (lane & 15)], ph.u[e], pl.u[e]); \
            }                                                                 \
            *(short8*)(smem + (WFBASE) + ((mt * 4 + r) * 2 + 0) * 1024 + lane * 16) = ph.v; \
            *(short8*)(smem + (WFBASE) + ((mt * 4 + r) * 2 + 1) * 1024 + lane * 16) = pl.v; \
        }                                                                     \
    }

// Per-mt reorder fence bounds the scheduler's hoisted ds_read transients.
#define GEMM_LAYER(WFBASE)                                                    \
    _Pragma("unroll")                                                         \
    for (int mt = 0; mt < 8; ++mt) acc[mt] = f32x4{0.f, 0.f, 0.f, 0.f};       \
    _Pragma("unroll")                                                         \
    for (int mt = 0; mt < 8; ++mt) {                                          \
        _Pragma("unroll")                                                     \
        for (int ks = 0; ks < 4; ++ks) {                                      \
            const short8 ah = *(const short8*)(smem + (WFBASE) + ((mt * 4 + ks) * 2 + 0) * 1024 + lane * 16); \
            const short8 al = *(const short8*)(smem + (WFBASE) + ((mt * 4 + ks) * 2 + 1) * 1024 + lane * 16); \
            acc[mt] = __builtin_amdgcn_mfma_f32_16x16x32_bf16(ah, bh[ks], acc[mt], 0, 0, 0); \
            acc[mt] = __builtin_amdgcn_mfma_f32_16x16x32_bf16(al, bh[ks], acc[mt], 0, 0, 0); \
            acc[mt] = __builtin_amdgcn_mfma_f32_16x16x32_bf16(ah, bl[ks], acc[mt], 0, 0, 0); \
        }                                                                     \
        asm volatile("" ::: "memory");                                        \
    }

template <bool USE_WS>
__global__
__attribute__((amdgpu_flat_work_group_size(NTH, NTH)))
__attribute__((amdgpu_waves_per_eu(2, 4)))
void eotqr_mfma(const float* __restrict__ Xg, const float* __restrict__ Ug,
                const float* __restrict__ Yg, const float* __restrict__ W0g,
                const float* __restrict__ b0g, const float* __restrict__ W1g,
                const float* __restrict__ b1g, const float* __restrict__ W2g,
                const float* __restrict__ b2g, const float* __restrict__ Woutg,
                const float* __restrict__ boutg, const float* __restrict__ hXg,
                const float* __restrict__ hYg, float* __restrict__ outg) {
    __shared__ __align__(16) char smem[LDS_BYTES];
    const int tid  = threadIdx.x;
    const int i    = blockIdx.x;
    const int lane = tid & 63;
    const int wid  = tid >> 6;      // 0..15
    const int g    = lane >> 4;

    // ---- init: small tables ----
    if (tid < HID) {
        ((float*)(smem + OFF_B1))[tid]   = b1g[tid];
        ((float*)(smem + OFF_B2))[tid]   = b2g[tid];
        ((float*)(smem + OFF_WOUT))[tid] = Woutg[tid];
        float a;
        if (USE_WS) {
            a = hXg[i * HID + tid];
        } else {
            a = b0g[tid];
            for (int f = 0; f < FDIM; ++f) a += Xg[i * FDIM + f] * W0g[f * HID + tid];
        }
        ((float*)(smem + OFF_HXI))[tid] = a;
    }
    if (!USE_WS)
        for (int e = tid; e < RDIM * HID; e += NTH)
            ((float*)(smem + OFF_W0R))[e] = W0g[FDIM * HID + e];

    // ---- stage W frags ----
    STAGE_LAYER(W1g, OFF_WF1, 0)
    STAGE_LAYER(W2g, OFF_WF2, 1)
    __syncthreads();

    const float bout0 = boutg[0];
    float Ui[RDIM];
#pragma unroll
    for (int r = 0; r < RDIM; ++r) Ui[r] = Ug[i * RDIM + r];

    float m_run = -INFINITY, s_run = 0.0f;

#pragma unroll 1
    for (int p = 0; p < NPASS; ++p) {
        const int jme = p * (NW * JW) + wid * JW + (lane & 15);
        const float4 ya = *(const float4*)(Yg + jme * RDIM);
        const float4 yb = *(const float4*)(Yg + jme * RDIM + 4);

        // ---- layer 0: B1 frags in registers ----
        short8 bh[4], bl[4];
#pragma unroll
        for (int ks = 0; ks < 4; ++ks) {
            float s[8];
            if (USE_WS) {
                const float* hb = hYg + (size_t)(p * NW + wid) * 2048 + (lane & 15) * 4;
                const float4 q0 = *(const float4*)(hb + (8 * ks + 2 * g + 0) * 64);
                const float4 q1 = *(const float4*)(hb + (8 * ks + 2 * g + 1) * 64);
                s[0] = q0.x; s[1] = q0.y; s[2] = q0.z; s[3] = q0.w;
                s[4] = q1.x; s[5] = q1.y; s[6] = q1.z; s[7] = q1.w;
            } else {
                const float* w0r = (const float*)(smem + OFF_W0R);
                const float yv[8] = {ya.x, ya.y, ya.z, ya.w, yb.x, yb.y, yb.z, yb.w};
#pragma unroll
                for (int e = 0; e < 8; ++e) {
                    float b = 0.0f;
#pragma unroll
                    for (int r = 0; r < RDIM; ++r)
                        b += yv[r] * w0r[r * HID + 32 * ks + 8 * g + e];
                    s[e] = b;
                }
            }
            const float4 hx0 = *(const float4*)(smem + OFF_HXI + (32 * ks + 8 * g) * 4);
            const float4 hx1 = *(const float4*)(smem + OFF_HXI + (32 * ks + 8 * g) * 4 + 16);
            s[0] += hx0.x; s[1] += hx0.y; s[2] += hx0.z; s[3] += hx0.w;
            s[4] += hx1.x; s[5] += hx1.y; s[6] += hx1.z; s[7] += hx1.w;
            union { unsigned short u[8]; short8 v; } ph, pl;
#pragma unroll
            for (int e = 0; e < 8; ++e) hilo(sp(s[e]), ph.u[e], pl.u[e]);
            bh[ks] = ph.v; bl[ks] = pl.v;
        }

        f32x4 acc[8];
        // ---- layer 1 ----
        GEMM_LAYER(OFF_WF1)

        // ---- epi1: C-frags -> B2 frags in-lane (rho at W2 staging) ----
#pragma unroll
        for (int ks = 0; ks < 4; ++ks) {
            union { unsigned short u[8]; short8 v; } ph, pl;
#pragma unroll
            for (int b = 0; b < 2; ++b) {
                const int mt = 2 * ks + b;
                const float4 bias = *(const float4*)(smem + OFF_B1 + (mt * 16 + 4 * g) * 4);
                const float bv[4] = {bias.x, bias.y, bias.z, bias.w};
#pragma unroll
                for (int e2 = 0; e2 < 4; ++e2)
                    hilo(sp(acc[mt][e2] + bv[e2]), ph.u[b * 4 + e2], pl.u[b * 4 + e2]);
            }
            bh[ks] = ph.v; bl[ks] = pl.v;
        }

        // ---- layer 2 ----
        GEMM_LAYER(OFF_WF2)

        // ---- epi2: psi partial over this lane's rows ----
        float ps = 0.0f;
#pragma unroll
        for (int mt = 0; mt < 8; ++mt) {
            const float4 b2v = *(const float4*)(smem + OFF_B2 + (mt * 16 + 4 * g) * 4);
            const float4 wov = *(const float4*)(smem + OFF_WOUT + (mt * 16 + 4 * g) * 4);
            const float bv[4] = {b2v.x, b2v.y, b2v.z, b2v.w};
            const float wv[4] = {wov.x, wov.y, wov.z, wov.w};
#pragma unroll
            for (int e2 = 0; e2 < 4; ++e2)
                ps += sp(acc[mt][e2] + bv[e2]) * wv[e2];
        }
        ps += __shfl_xor(ps, 16);
        ps += __shfl_xor(ps, 32);   // full 128-row sum; all lanes hold psi[j]

        float cost = Ui[0] * ya.x + Ui[1] * ya.y + Ui[2] * ya.z + Ui[3] * ya.w +
                     Ui[4] * yb.x + Ui[5] * yb.y + Ui[6] * yb.z + Ui[7] * yb.w;
        const float slk = cost - ps - bout0;

        // ---- online LSE within the 16-lane group ----
        float t = slk;
#pragma unroll
        for (int d = 1; d <= 8; d <<= 1) t = fmaxf(t, __shfl_xor(t, d));
        const float nm = fmaxf(m_run, t);
        float e = __expf((slk - nm) * INV_EPS);
#pragma unroll
        for (int d = 1; d <= 8; d <<= 1) e += __shfl_xor(e, d);
        s_run = s_run * __expf((m_run - nm) * INV_EPS) + e;
        m_run = nm;
    }

    // ---- cross-wave combine ----
    if (lane == 0) {
        ((float*)(smem + OFF_LSE))[wid]      = m_run;
        ((float*)(smem + OFF_LSE))[NW + wid] = s_run;
    }
    __syncthreads();
    if (tid == 0) {
        const float* lm = (const float*)(smem + OFF_LSE);
        float M = -INFINITY;
#pragma unroll
        for (int w = 0; w < NW; ++w) M = fmaxf(M, lm[w]);
        float S = 0.0f;
#pragma unroll
        for (int w = 0; w < NW; ++w) S += lm[NW + w] * __expf((lm[w] - M) * INV_EPS);
        outg[i] = EPS_F * (logf(S) - logf((float)NPTS)) + M;
    }
}

extern "C" void kernel_launch(void* const* d_in, const int* in_sizes, int n_in,
                              void* d_out, int out_size, void* d_ws, size_t ws_size,
                              hipStream_t stream) {
    const float* X    = (const float*)d_in[0];
    const float* U    = (const float*)d_in[1];
    const float* Y    = (const float*)d_in[2];
    const float* W0   = (const float*)d_in[3];
    const float* b0   = (const float*)d_in[4];
    const float* W1   = (const float*)d_in[5];
    const float* b1   = (const float*)d_in[6];
    const float* W2   = (const float*)d_in[7];
    const float* b2   = (const float*)d_in[8];
    const float* Wout = (const float*)d_in[9];
    const float* bout = (const float*)d_in[10];
    float* out = (float*)d_out;

    const size_t need_ws = (size_t)2 * NPTS * HID * sizeof(float);  // 1 MiB
    if (ws_size >= need_ws) {
        float* hX  = (float*)d_ws;
        float* hYP = hX + NPTS * HID;
        hipLaunchKernelGGL(eotqr_pre, dim3(NPTS), dim3(HID), 0, stream, X, Y, W0, b0, hX, hYP);
        hipLaunchKernelGGL(eotqr_mfma<true>, dim3(NPTS), dim3(NTH), 0, stream,
                           X, U, Y, W0, b0, W1, b1, W2, b2, Wout, bout, hX, hYP, out);
    } else {
        hipLaunchKernelGGL(eotqr_mfma<false>, dim3(NPTS), dim3(NTH), 0, stream,
                           X, U, Y, W0, b0, W1, b1, W2, b2, Wout, bout,
                           (const float*)nullptr, (const float*)nullptr, out);
    }
}

// Round 12
// 299.577 us; speedup vs baseline: 6.1006x; 1.1381x over previous
//
#include <hip/hip_runtime.h>
#include <hip/hip_bf16.h>

// EntropicOTQuantileRegression — R12. Single lever vs R11: drop the H-side
// lo term. H = single bf16; W stays hi/lo (staged once) -> 2-product MFMA
// (Whi*H + Wlo*H). Cuts MFMA work 33%, halves H conversions, frees bl regs
// (spill relief at 4 waves/SIMD). Expected absmax ~3e-3 (H quant 2^-9,
// averaged over K=128, smoothed by eps-logsumexp) — the stated gamble.

#define NPTS 1024
#define FDIM 64
#define RDIM 8
#define HID  128
#define NTH  1024
#define NW   16
#define JW   16
#define NPASS (NPTS / (NW * JW))   // 4
#define EPS_F 0.1f
#define INV_EPS 10.0f

typedef __attribute__((ext_vector_type(8))) short short8;   // 8 bf16
typedef __attribute__((ext_vector_type(4))) float f32x4;

// LDS byte offsets
#define OFF_WF1  0         // 65536: W1 frags [mt8][ks4][hi/lo][lane*16]
#define OFF_WF2  65536     // 65536: W2 frags (rho-permuted k rows)
#define OFF_STG  131072    // 16384: init staging chunk (32 rows x 128 f32)
#define OFF_HXI  147456    // 512
#define OFF_B1   147968    // 512
#define OFF_B2   148480    // 512
#define OFF_WOUT 148992    // 512
#define OFF_W0R  149504    // 4096 (fallback only)
#define OFF_LSE  153600    // 128 (16 waves x {m,s})
#define LDS_BYTES 153728   // < 163840

__device__ __forceinline__ float sp(float x) {
    return fmaxf(x, 0.0f) + __logf(1.0f + __expf(-fabsf(x)));
}
__device__ __forceinline__ float bcf(unsigned x) { return __builtin_bit_cast(float, x); }
__device__ __forceinline__ unsigned short bf16c(float x) {
    return __builtin_bit_cast(unsigned short, __float2bfloat16(x));
}
// hi/lo split (W staging only): hi = bf16(x), lo = bf16(x - hi).
__device__ __forceinline__ void hilo(float x, unsigned short& h, unsigned short& l) {
    h = bf16c(x);
    l = bf16c(x - bcf(((unsigned)h) << 16));
}

// pre-kernel: hX[n][c] natural; hY in the coalesced frag-read layout:
// hYP[(n>>4)*2048 + (c>>2)*64 + (n&15)*4 + (c&3)]
__global__ void eotqr_pre(const float* __restrict__ Xg, const float* __restrict__ Yg,
                          const float* __restrict__ W0g, const float* __restrict__ b0g,
                          float* __restrict__ hX, float* __restrict__ hYP) {
    const int n = blockIdx.x, c = threadIdx.x;
    float a = b0g[c];
    for (int f = 0; f < FDIM; ++f) a += Xg[n * FDIM + f] * W0g[f * HID + c];
    hX[n * HID + c] = a;
    float b = 0.0f;
#pragma unroll
    for (int r = 0; r < RDIM; ++r) b += Yg[n * RDIM + r] * W0g[(FDIM + r) * HID + c];
    hYP[(n >> 4) * 2048 + (c >> 2) * 64 + (n & 15) * 4 + (c & 3)] = b;
}

// Stage one layer's W into frag-linear LDS. Chunk r = raw rows [32r,32r+32)
// == frags ks=r. Waves 0..7 build mt=wid; waves 8..15 only help the copy.
#define STAGE_LAYER(WSRC, WFBASE, IS_W2)                                      \
    for (int r = 0; r < 4; ++r) {                                             \
        __syncthreads();                                                      \
        for (int e4 = tid; e4 < 1024; e4 += NTH)                              \
            ((float4*)(smem + OFF_STG))[e4] =                                 \
                ((const float4*)((WSRC) + r * 32 * HID))[e4];                 \
        __syncthreads();                                                      \
        if (wid < 8) {                                                        \
            const float* stg = (const float*)(smem + OFF_STG);                \
            const int mt = wid;                                               \
            union { unsigned short u[8]; short8 v; } ph, pl;                  \
            _Pragma("unroll")                                                 \
            for (int e = 0; e < 8; ++e) {                                     \
                const int kloc = (IS_W2) ? ((e >= 4) * 16 + g * 4 + (e & 3))  \
                                         : (g * 8 + e);                       \
                hilo(stg[kloc * HID + mt * 16 + (lane & 15)], ph.u[e], pl.u[e]); \
            }                                                                 \
            *(short8*)(smem + (WFBASE) + ((mt * 4 + r) * 2 + 0) * 1024 + lane * 16) = ph.v; \
            *(short8*)(smem + (WFBASE) + ((mt * 4 + r) * 2 + 1) * 1024 + lane * 16) = pl.v; \
        }                                                                     \
    }

// 2-product: (Whi + Wlo) x H. Per-mt reorder fence bounds ds_read hoisting.
#define GEMM_LAYER(WFBASE)                                                    \
    _Pragma("unroll")                                                         \
    for (int mt = 0; mt < 8; ++mt) acc[mt] = f32x4{0.f, 0.f, 0.f, 0.f};       \
    _Pragma("unroll")                                                         \
    for (int mt = 0; mt < 8; ++mt) {                                          \
        _Pragma("unroll")                                                     \
        for (int ks = 0; ks < 4; ++ks) {                                      \
            const short8 ah = *(const short8*)(smem + (WFBASE) + ((mt * 4 + ks) * 2 + 0) * 1024 + lane * 16); \
            const short8 al = *(const short8*)(smem + (WFBASE) + ((mt * 4 + ks) * 2 + 1) * 1024 + lane * 16); \
            acc[mt] = __builtin_amdgcn_mfma_f32_16x16x32_bf16(ah, bh[ks], acc[mt], 0, 0, 0); \
            acc[mt] = __builtin_amdgcn_mfma_f32_16x16x32_bf16(al, bh[ks], acc[mt], 0, 0, 0); \
        }                                                                     \
        asm volatile("" ::: "memory");                                        \
    }

template <bool USE_WS>
__global__
__attribute__((amdgpu_flat_work_group_size(NTH, NTH)))
__attribute__((amdgpu_waves_per_eu(2, 4)))
void eotqr_mfma(const float* __restrict__ Xg, const float* __restrict__ Ug,
                const float* __restrict__ Yg, const float* __restrict__ W0g,
                const float* __restrict__ b0g, const float* __restrict__ W1g,
                const float* __restrict__ b1g, const float* __restrict__ W2g,
                const float* __restrict__ b2g, const float* __restrict__ Woutg,
                const float* __restrict__ boutg, const float* __restrict__ hXg,
                const float* __restrict__ hYg, float* __restrict__ outg) {
    __shared__ __align__(16) char smem[LDS_BYTES];
    const int tid  = threadIdx.x;
    const int i    = blockIdx.x;
    const int lane = tid & 63;
    const int wid  = tid >> 6;      // 0..15
    const int g    = lane >> 4;

    // ---- init: small tables ----
    if (tid < HID) {
        ((float*)(smem + OFF_B1))[tid]   = b1g[tid];
        ((float*)(smem + OFF_B2))[tid]   = b2g[tid];
        ((float*)(smem + OFF_WOUT))[tid] = Woutg[tid];
        float a;
        if (USE_WS) {
            a = hXg[i * HID + tid];
        } else {
            a = b0g[tid];
            for (int f = 0; f < FDIM; ++f) a += Xg[i * FDIM + f] * W0g[f * HID + tid];
        }
        ((float*)(smem + OFF_HXI))[tid] = a;
    }
    if (!USE_WS)
        for (int e = tid; e < RDIM * HID; e += NTH)
            ((float*)(smem + OFF_W0R))[e] = W0g[FDIM * HID + e];

    // ---- stage W frags ----
    STAGE_LAYER(W1g, OFF_WF1, 0)
    STAGE_LAYER(W2g, OFF_WF2, 1)
    __syncthreads();

    const float bout0 = boutg[0];
    float Ui[RDIM];
#pragma unroll
    for (int r = 0; r < RDIM; ++r) Ui[r] = Ug[i * RDIM + r];

    float m_run = -INFINITY, s_run = 0.0f;

#pragma unroll 1
    for (int p = 0; p < NPASS; ++p) {
        const int jme = p * (NW * JW) + wid * JW + (lane & 15);
        const float4 ya = *(const float4*)(Yg + jme * RDIM);
        const float4 yb = *(const float4*)(Yg + jme * RDIM + 4);

        // ---- layer 0: B1 frags (single bf16) in registers ----
        short8 bh[4];
#pragma unroll
        for (int ks = 0; ks < 4; ++ks) {
            float s[8];
            if (USE_WS) {
                const float* hb = hYg + (size_t)(p * NW + wid) * 2048 + (lane & 15) * 4;
                const float4 q0 = *(const float4*)(hb + (8 * ks + 2 * g + 0) * 64);
                const float4 q1 = *(const float4*)(hb + (8 * ks + 2 * g + 1) * 64);
                s[0] = q0.x; s[1] = q0.y; s[2] = q0.z; s[3] = q0.w;
                s[4] = q1.x; s[5] = q1.y; s[6] = q1.z; s[7] = q1.w;
            } else {
                const float* w0r = (const float*)(smem + OFF_W0R);
                const float yv[8] = {ya.x, ya.y, ya.z, ya.w, yb.x, yb.y, yb.z, yb.w};
#pragma unroll
                for (int e = 0; e < 8; ++e) {
                    float b = 0.0f;
#pragma unroll
                    for (int r = 0; r < RDIM; ++r)
                        b += yv[r] * w0r[r * HID + 32 * ks + 8 * g + e];
                    s[e] = b;
                }
            }
            const float4 hx0 = *(const float4*)(smem + OFF_HXI + (32 * ks + 8 * g) * 4);
            const float4 hx1 = *(const float4*)(smem + OFF_HXI + (32 * ks + 8 * g) * 4 + 16);
            s[0] += hx0.x; s[1] += hx0.y; s[2] += hx0.z; s[3] += hx0.w;
            s[4] += hx1.x; s[5] += hx1.y; s[6] += hx1.z; s[7] += hx1.w;
            union { unsigned short u[8]; short8 v; } ph;
#pragma unroll
            for (int e = 0; e < 8; ++e) ph.u[e] = bf16c(sp(s[e]));
            bh[ks] = ph.v;
        }

        f32x4 acc[8];
        // ---- layer 1 ----
        GEMM_LAYER(OFF_WF1)

        // ---- epi1: C-frags -> B2 frags in-lane (rho at W2 staging) ----
#pragma unroll
        for (int ks = 0; ks < 4; ++ks) {
            union { unsigned short u[8]; short8 v; } ph;
#pragma unroll
            for (int b = 0; b < 2; ++b) {
                const int mt = 2 * ks + b;
                const float4 bias = *(const float4*)(smem + OFF_B1 + (mt * 16 + 4 * g) * 4);
                const float bv[4] = {bias.x, bias.y, bias.z, bias.w};
#pragma unroll
                for (int e2 = 0; e2 < 4; ++e2)
                    ph.u[b * 4 + e2] = bf16c(sp(acc[mt][e2] + bv[e2]));
            }
            bh[ks] = ph.v;
        }

        // ---- layer 2 ----
        GEMM_LAYER(OFF_WF2)

        // ---- epi2: psi partial over this lane's rows ----
        float ps = 0.0f;
#pragma unroll
        for (int mt = 0; mt < 8; ++mt) {
            const float4 b2v = *(const float4*)(smem + OFF_B2 + (mt * 16 + 4 * g) * 4);
            const float4 wov = *(const float4*)(smem + OFF_WOUT + (mt * 16 + 4 * g) * 4);
            const float bv[4] = {b2v.x, b2v.y, b2v.z, b2v.w};
            const float wv[4] = {wov.x, wov.y, wov.z, wov.w};
#pragma unroll
            for (int e2 = 0; e2 < 4; ++e2)
                ps += sp(acc[mt][e2] + bv[e2]) * wv[e2];
        }
        ps += __shfl_xor(ps, 16);
        ps += __shfl_xor(ps, 32);   // full 128-row sum; all lanes hold psi[j]

        float cost = Ui[0] * ya.x + Ui[1] * ya.y + Ui[2] * ya.z + Ui[3] * ya.w +
                     Ui[4] * yb.x + Ui[5] * yb.y + Ui[6] * yb.z + Ui[7] * yb.w;
        const float slk = cost - ps - bout0;

        // ---- online LSE within the 16-lane group ----
        float t = slk;
#pragma unroll
        for (int d = 1; d <= 8; d <<= 1) t = fmaxf(t, __shfl_xor(t, d));
        const float nm = fmaxf(m_run, t);
        float e = __expf((slk - nm) * INV_EPS);
#pragma unroll
        for (int d = 1; d <= 8; d <<= 1) e += __shfl_xor(e, d);
        s_run = s_run * __expf((m_run - nm) * INV_EPS) + e;
        m_run = nm;
    }

    // ---- cross-wave combine ----
    if (lane == 0) {
        ((float*)(smem + OFF_LSE))[wid]      = m_run;
        ((float*)(smem + OFF_LSE))[NW + wid] = s_run;
    }
    __syncthreads();
    if (tid == 0) {
        const float* lm = (const float*)(smem + OFF_LSE);
        float M = -INFINITY;
#pragma unroll
        for (int w = 0; w < NW; ++w) M = fmaxf(M, lm[w]);
        float S = 0.0f;
#pragma unroll
        for (int w = 0; w < NW; ++w) S += lm[NW + w] * __expf((lm[w] - M) * INV_EPS);
        outg[i] = EPS_F * (logf(S) - logf((float)NPTS)) + M;
    }
}

extern "C" void kernel_launch(void* const* d_in, const int* in_sizes, int n_in,
                              void* d_out, int out_size, void* d_ws, size_t ws_size,
                              hipStream_t stream) {
    const float* X    = (const float*)d_in[0];
    const float* U    = (const float*)d_in[1];
    const float* Y    = (const float*)d_in[2];
    const float* W0   = (const float*)d_in[3];
    const float* b0   = (const float*)d_in[4];
    const float* W1   = (const float*)d_in[5];
    const float* b1   = (const float*)d_in[6];
    const float* W2   = (const float*)d_in[7];
    const float* b2   = (const float*)d_in[8];
    const float* Wout = (const float*)d_in[9];
    const float* bout = (const float*)d_in[10];
    float* out = (float*)d_out;

    const size_t need_ws = (size_t)2 * NPTS * HID * sizeof(float);  // 1 MiB
    if (ws_size >= need_ws) {
        float* hX  = (float*)d_ws;
        float* hYP = hX + NPTS * HID;
        hipLaunchKernelGGL(eotqr_pre, dim3(NPTS), dim3(HID), 0, stream, X, Y, W0, b0, hX, hYP);
        hipLaunchKernelGGL(eotqr_mfma<true>, dim3(NPTS), dim3(NTH), 0, stream,
                           X, U, Y, W0, b0, W1, b1, W2, b2, Wout, bout, hX, hYP, out);
    } else {
        hipLaunchKernelGGL(eotqr_mfma<false>, dim3(NPTS), dim3(NTH), 0, stream,
                           X, U, Y, W0, b0, W1, b1, W2, b2, Wout, bout,
                           (const float*)nullptr, (const float*)nullptr, out);
    }
}

// Round 13
// 269.501 us; speedup vs baseline: 6.7814x; 1.1116x over previous
//
#include <hip/hip_runtime.h>
#include <hip/hip_bf16.h>

// EntropicOTQuantileRegression — R13. Two levers on R12:
//  (1) JW 16->32 at NTH=1024 (R10 evidence: A-frag-read sharing worth ~50us;
//      now fits the 128-VGPR budget since H-lo dropped freed 32 regs).
//  (2) softplus in exp2-domain: fold log2e into hX/hY/b1/b2, ln2 into Wout.
//      sp'(t)=fmax(t,0)+log2(1+2^-|t|) = 5 insts via native v_exp/v_log.
// Math identical to R12 within 1e-7 (absmax stays ~0.0625, from H-quant).

#define NPTS 1024
#define FDIM 64
#define RDIM 8
#define HID  128
#define NTH  1024
#define NW   16
#define JW   32
#define NPASS (NPTS / (NW * JW))   // 2
#define EPS_F 0.1f
#define INV_EPS 10.0f
#define LOG2E 1.44269504088896340736f
#define LN2   0.69314718055994530942f

typedef __attribute__((ext_vector_type(8))) short short8;   // 8 bf16
typedef __attribute__((ext_vector_type(4))) float f32x4;

// LDS byte offsets
#define OFF_WF1  0         // 65536: W1 frags [mt8][ks4][hi/lo][lane*16]
#define OFF_WF2  65536     // 65536: W2 frags (rho-permuted k rows)
#define OFF_STG  131072    // 16384: init staging chunk (32 rows x 128 f32)
#define OFF_HXI  147456    // 512
#define OFF_B1   147968    // 512
#define OFF_B2   148480    // 512
#define OFF_WOUT 148992    // 512
#define OFF_W0R  149504    // 4096 (fallback only)
#define OFF_LSE  153600    // 128 (16 waves x {m,s})
#define LDS_BYTES 153728   // < 163840

// exp2-domain softplus: sp(x) = ln2 * sp2(x*log2e); scales folded at staging.
__device__ __forceinline__ float sp2(float t) {
    float z;
    asm("v_exp_f32_e64 %0, -abs(%1)" : "=v"(z) : "v"(t));  // 2^(-|t|)
    z += 1.0f;
    float r;
    asm("v_log_f32 %0, %1" : "=v"(r) : "v"(z));            // log2(1+2^-|t|)
    return fmaxf(t, 0.0f) + r;
}
__device__ __forceinline__ float bcf(unsigned x) { return __builtin_bit_cast(float, x); }
__device__ __forceinline__ unsigned short bf16c(float x) {
    return __builtin_bit_cast(unsigned short, __float2bfloat16(x));
}
// hi/lo split (W staging only): hi = bf16(x), lo = bf16(x - hi).
__device__ __forceinline__ void hilo(float x, unsigned short& h, unsigned short& l) {
    h = bf16c(x);
    l = bf16c(x - bcf(((unsigned)h) << 16));
}

// pre-kernel (exp2-domain: outputs pre-scaled by log2e):
// hX[n][c] natural; hY in frag-read layout hYP[(n>>4)*2048+(c>>2)*64+(n&15)*4+(c&3)]
__global__ void eotqr_pre(const float* __restrict__ Xg, const float* __restrict__ Yg,
                          const float* __restrict__ W0g, const float* __restrict__ b0g,
                          float* __restrict__ hX, float* __restrict__ hYP) {
    const int n = blockIdx.x, c = threadIdx.x;
    float a = b0g[c];
    for (int f = 0; f < FDIM; ++f) a += Xg[n * FDIM + f] * W0g[f * HID + c];
    hX[n * HID + c] = a * LOG2E;
    float b = 0.0f;
#pragma unroll
    for (int r = 0; r < RDIM; ++r) b += Yg[n * RDIM + r] * W0g[(FDIM + r) * HID + c];
    hYP[(n >> 4) * 2048 + (c >> 2) * 64 + (n & 15) * 4 + (c & 3)] = b * LOG2E;
}

// Stage one layer's W into frag-linear LDS (W frags NOT scaled — the ln2*log2e
// between consecutive sp' layers cancels). Waves 0..7 build mt=wid.
#define STAGE_LAYER(WSRC, WFBASE, IS_W2)                                      \
    for (int r = 0; r < 4; ++r) {                                             \
        __syncthreads();                                                      \
        for (int e4 = tid; e4 < 1024; e4 += NTH)                              \
            ((float4*)(smem + OFF_STG))[e4] =                                 \
                ((const float4*)((WSRC) + r * 32 * HID))[e4];                 \
        __syncthreads();                                                      \
        if (wid < 8) {                                                        \
            const float* stg = (const float*)(smem + OFF_STG);                \
            const int mt = wid;                                               \
            union { unsigned short u[8]; short8 v; } ph, pl;                  \
            _Pragma("unroll")                                                 \
            for (int e = 0; e < 8; ++e) {                                     \
                const int kloc = (IS_W2) ? ((e >= 4) * 16 + g * 4 + (e & 3))  \
                                         : (g * 8 + e);                       \
                hilo(stg[kloc * HID + mt * 16 + (lane & 15)], ph.u[e], pl.u[e]); \
            }                                                                 \
            *(short8*)(smem + (WFBASE) + ((mt * 4 + r) * 2 + 0) * 1024 + lane * 16) = ph.v; \
            *(short8*)(smem + (WFBASE) + ((mt * 4 + r) * 2 + 1) * 1024 + lane * 16) = pl.v; \
        }                                                                     \
    }

// 2-product x 2 j-groups: each A-frag pair feeds 4 MFMAs, alternating
// acc0/acc1 (independent). Per-mt reorder fence bounds transients.
#define GEMM_LAYER(WFBASE)                                                    \
    _Pragma("unroll")                                                         \
    for (int mt = 0; mt < 8; ++mt) {                                          \
        acc0[mt] = f32x4{0.f, 0.f, 0.f, 0.f};                                 \
        acc1[mt] = f32x4{0.f, 0.f, 0.f, 0.f};                                 \
    }                                                                         \
    _Pragma("unroll")                                                         \
    for (int mt = 0; mt < 8; ++mt) {                                          \
        _Pragma("unroll")                                                     \
        for (int ks = 0; ks < 4; ++ks) {                                      \
            const short8 ah = *(const short8*)(smem + (WFBASE) + ((mt * 4 + ks) * 2 + 0) * 1024 + lane * 16); \
            const short8 al = *(const short8*)(smem + (WFBASE) + ((mt * 4 + ks) * 2 + 1) * 1024 + lane * 16); \
            acc0[mt] = __builtin_amdgcn_mfma_f32_16x16x32_bf16(ah, bh0[ks], acc0[mt], 0, 0, 0); \
            acc1[mt] = __builtin_amdgcn_mfma_f32_16x16x32_bf16(ah, bh1[ks], acc1[mt], 0, 0, 0); \
            acc0[mt] = __builtin_amdgcn_mfma_f32_16x16x32_bf16(al, bh0[ks], acc0[mt], 0, 0, 0); \
            acc1[mt] = __builtin_amdgcn_mfma_f32_16x16x32_bf16(al, bh1[ks], acc1[mt], 0, 0, 0); \
        }                                                                     \
        asm volatile("" ::: "memory");                                        \
    }

template <bool USE_WS>
__global__
__attribute__((amdgpu_flat_work_group_size(NTH, NTH)))
__attribute__((amdgpu_waves_per_eu(2, 4)))
void eotqr_mfma(const float* __restrict__ Xg, const float* __restrict__ Ug,
                const float* __restrict__ Yg, const float* __restrict__ W0g,
                const float* __restrict__ b0g, const float* __restrict__ W1g,
                const float* __restrict__ b1g, const float* __restrict__ W2g,
                const float* __restrict__ b2g, const float* __restrict__ Woutg,
                const float* __restrict__ boutg, const float* __restrict__ hXg,
                const float* __restrict__ hYg, float* __restrict__ outg) {
    __shared__ __align__(16) char smem[LDS_BYTES];
    const int tid  = threadIdx.x;
    const int i    = blockIdx.x;
    const int lane = tid & 63;
    const int wid  = tid >> 6;      // 0..15
    const int g    = lane >> 4;

    // ---- init: small tables (exp2-domain scaling folded here) ----
    if (tid < HID) {
        ((float*)(smem + OFF_B1))[tid]   = b1g[tid] * LOG2E;
        ((float*)(smem + OFF_B2))[tid]   = b2g[tid] * LOG2E;
        ((float*)(smem + OFF_WOUT))[tid] = Woutg[tid] * LN2;
        float a;
        if (USE_WS) {
            a = hXg[i * HID + tid];           // pre-scaled in pre-kernel
        } else {
            a = b0g[tid];
            for (int f = 0; f < FDIM; ++f) a += Xg[i * FDIM + f] * W0g[f * HID + tid];
            a *= LOG2E;
        }
        ((float*)(smem + OFF_HXI))[tid] = a;
    }
    if (!USE_WS)
        for (int e = tid; e < RDIM * HID; e += NTH)
            ((float*)(smem + OFF_W0R))[e] = W0g[FDIM * HID + e] * LOG2E;

    // ---- stage W frags ----
    STAGE_LAYER(W1g, OFF_WF1, 0)
    STAGE_LAYER(W2g, OFF_WF2, 1)
    __syncthreads();

    const float bout0 = boutg[0];
    float Ui[RDIM];
#pragma unroll
    for (int r = 0; r < RDIM; ++r) Ui[r] = Ug[i * RDIM + r];

    float m_run = -INFINITY, s_run = 0.0f;

#pragma unroll 1
    for (int p = 0; p < NPASS; ++p) {
        const int jme0 = p * (NW * JW) + wid * JW + (lane & 15);
        const int jme1 = jme0 + 16;
        const float4 ya0 = *(const float4*)(Yg + jme0 * RDIM);
        const float4 yb0 = *(const float4*)(Yg + jme0 * RDIM + 4);
        const float4 ya1 = *(const float4*)(Yg + jme1 * RDIM);
        const float4 yb1 = *(const float4*)(Yg + jme1 * RDIM + 4);

        // ---- layer 0: two B1 frag sets (single bf16) ----
        short8 bh0[4], bh1[4];
#pragma unroll
        for (int ks = 0; ks < 4; ++ks) {
            float s0[8], s1[8];
            if (USE_WS) {
                const int gi0 = (p * NW + wid) * 2;
                const float* hb0 = hYg + (size_t)gi0 * 2048 + (lane & 15) * 4;
                const float* hb1 = hb0 + 2048;
                const float4 q00 = *(const float4*)(hb0 + (8 * ks + 2 * g + 0) * 64);
                const float4 q01 = *(const float4*)(hb0 + (8 * ks + 2 * g + 1) * 64);
                const float4 q10 = *(const float4*)(hb1 + (8 * ks + 2 * g + 0) * 64);
                const float4 q11 = *(const float4*)(hb1 + (8 * ks + 2 * g + 1) * 64);
                s0[0] = q00.x; s0[1] = q00.y; s0[2] = q00.z; s0[3] = q00.w;
                s0[4] = q01.x; s0[5] = q01.y; s0[6] = q01.z; s0[7] = q01.w;
                s1[0] = q10.x; s1[1] = q10.y; s1[2] = q10.z; s1[3] = q10.w;
                s1[4] = q11.x; s1[5] = q11.y; s1[6] = q11.z; s1[7] = q11.w;
            } else {
                const float* w0r = (const float*)(smem + OFF_W0R);
                const float yv0[8] = {ya0.x, ya0.y, ya0.z, ya0.w, yb0.x, yb0.y, yb0.z, yb0.w};
                const float yv1[8] = {ya1.x, ya1.y, ya1.z, ya1.w, yb1.x, yb1.y, yb1.z, yb1.w};
#pragma unroll
                for (int e = 0; e < 8; ++e) {
                    float b0a = 0.0f, b1a = 0.0f;
#pragma unroll
                    for (int r = 0; r < RDIM; ++r) {
                        const float w = w0r[r * HID + 32 * ks + 8 * g + e];
                        b0a += yv0[r] * w;
                        b1a += yv1[r] * w;
                    }
                    s0[e] = b0a; s1[e] = b1a;
                }
            }
            const float4 hx0 = *(const float4*)(smem + OFF_HXI + (32 * ks + 8 * g) * 4);
            const float4 hx1 = *(const float4*)(smem + OFF_HXI + (32 * ks + 8 * g) * 4 + 16);
            const float hxv[8] = {hx0.x, hx0.y, hx0.z, hx0.w, hx1.x, hx1.y, hx1.z, hx1.w};
            union { unsigned short u[8]; short8 v; } p0, p1;
#pragma unroll
            for (int e = 0; e < 8; ++e) {
                p0.u[e] = bf16c(sp2(s0[e] + hxv[e]));
                p1.u[e] = bf16c(sp2(s1[e] + hxv[e]));
            }
            bh0[ks] = p0.v; bh1[ks] = p1.v;
        }

        f32x4 acc0[8], acc1[8];
        // ---- layer 1 ----
        GEMM_LAYER(OFF_WF1)

        // ---- epi1: C-frags -> B2 frags in-lane (rho at W2 staging) ----
#pragma unroll
        for (int ks = 0; ks < 4; ++ks) {
            union { unsigned short u[8]; short8 v; } p0, p1;
#pragma unroll
            for (int b = 0; b < 2; ++b) {
                const int mt = 2 * ks + b;
                const float4 bias = *(const float4*)(smem + OFF_B1 + (mt * 16 + 4 * g) * 4);
                const float bv[4] = {bias.x, bias.y, bias.z, bias.w};
#pragma unroll
                for (int e2 = 0; e2 < 4; ++e2) {
                    p0.u[b * 4 + e2] = bf16c(sp2(acc0[mt][e2] + bv[e2]));
                    p1.u[b * 4 + e2] = bf16c(sp2(acc1[mt][e2] + bv[e2]));
                }
            }
            bh0[ks] = p0.v; bh1[ks] = p1.v;
        }

        // ---- layer 2 ----
        GEMM_LAYER(OFF_WF2)

        // ---- epi2: psi partials (wouts pre-scaled by ln2) ----
        float ps0 = 0.0f, ps1 = 0.0f;
#pragma unroll
        for (int mt = 0; mt < 8; ++mt) {
            const float4 b2v = *(const float4*)(smem + OFF_B2 + (mt * 16 + 4 * g) * 4);
            const float4 wov = *(const float4*)(smem + OFF_WOUT + (mt * 16 + 4 * g) * 4);
            const float bv[4] = {b2v.x, b2v.y, b2v.z, b2v.w};
            const float wv[4] = {wov.x, wov.y, wov.z, wov.w};
#pragma unroll
            for (int e2 = 0; e2 < 4; ++e2) {
                ps0 += sp2(acc0[mt][e2] + bv[e2]) * wv[e2];
                ps1 += sp2(acc1[mt][e2] + bv[e2]) * wv[e2];
            }
        }
        ps0 += __shfl_xor(ps0, 16); ps0 += __shfl_xor(ps0, 32);
        ps1 += __shfl_xor(ps1, 16); ps1 += __shfl_xor(ps1, 32);

        const float cost0 = Ui[0]*ya0.x + Ui[1]*ya0.y + Ui[2]*ya0.z + Ui[3]*ya0.w +
                            Ui[4]*yb0.x + Ui[5]*yb0.y + Ui[6]*yb0.z + Ui[7]*yb0.w;
        const float cost1 = Ui[0]*ya1.x + Ui[1]*ya1.y + Ui[2]*ya1.z + Ui[3]*ya1.w +
                            Ui[4]*yb1.x + Ui[5]*yb1.y + Ui[6]*yb1.z + Ui[7]*yb1.w;
        const float slk0 = cost0 - ps0 - bout0;
        const float slk1 = cost1 - ps1 - bout0;

        // ---- online LSE within the 16-lane group (32 distinct j) ----
        float t = fmaxf(slk0, slk1);
#pragma unroll
        for (int d = 1; d <= 8; d <<= 1) t = fmaxf(t, __shfl_xor(t, d));
        const float nm = fmaxf(m_run, t);
        float e = __expf((slk0 - nm) * INV_EPS) + __expf((slk1 - nm) * INV_EPS);
#pragma unroll
        for (int d = 1; d <= 8; d <<= 1) e += __shfl_xor(e, d);
        s_run = s_run * __expf((m_run - nm) * INV_EPS) + e;
        m_run = nm;
    }

    // ---- cross-wave combine ----
    if (lane == 0) {
        ((float*)(smem + OFF_LSE))[wid]      = m_run;
        ((float*)(smem + OFF_LSE))[NW + wid] = s_run;
    }
    __syncthreads();
    if (tid == 0) {
        const float* lm = (const float*)(smem + OFF_LSE);
        float M = -INFINITY;
#pragma unroll
        for (int w = 0; w < NW; ++w) M = fmaxf(M, lm[w]);
        float S = 0.0f;
#pragma unroll
        for (int w = 0; w < NW; ++w) S += lm[NW + w] * __expf((lm[w] - M) * INV_EPS);
        outg[i] = EPS_F * (logf(S) - logf((float)NPTS)) + M;
    }
}

extern "C" void kernel_launch(void* const* d_in, const int* in_sizes, int n_in,
                              void* d_out, int out_size, void* d_ws, size_t ws_size,
                              hipStream_t stream) {
    const float* X    = (const float*)d_in[0];
    const float* U    = (const float*)d_in[1];
    const float* Y    = (const float*)d_in[2];
    const float* W0   = (const float*)d_in[3];
    const float* b0   = (const float*)d_in[4];
    const float* W1   = (const float*)d_in[5];
    const float* b1   = (const float*)d_in[6];
    const float* W2   = (const float*)d_in[7];
    const float* b2   = (const float*)d_in[8];
    const float* Wout = (const float*)d_in[9];
    const float* bout = (const float*)d_in[10];
    float* out = (float*)d_out;

    const size_t need_ws = (size_t)2 * NPTS * HID * sizeof(float);  // 1 MiB
    if (ws_size >= need_ws) {
        float* hX  = (float*)d_ws;
        float* hYP = hX + NPTS * HID;
        hipLaunchKernelGGL(eotqr_pre, dim3(NPTS), dim3(HID), 0, stream, X, Y, W0, b0, hX, hYP);
        hipLaunchKernelGGL(eotqr_mfma<true>, dim3(NPTS), dim3(NTH), 0, stream,
                           X, U, Y, W0, b0, W1, b1, W2, b2, Wout, bout, hX, hYP, out);
    } else {
        hipLaunchKernelGGL(eotqr_mfma<false>, dim3(NPTS), dim3(NTH), 0, stream,
                           X, U, Y, W0, b0, W1, b1, W2, b2, Wout, bout,
                           (const float*)nullptr, (const float*)nullptr, out);
    }
}

// Round 14
// 211.940 us; speedup vs baseline: 8.6232x; 1.2716x over previous
//
#include <hip/hip_runtime.h>
#include <hip/hip_bf16.h>

// EntropicOTQuantileRegression — R14. Single variable vs R13: JW 32->16.
// R13 proved sp2 (exp2-domain softplus) cut VALU-busy-time 275->131us, but
// JW=32 at NTH=1024 spilled (allocator pins 64 VGPR at 1024 threads; JW=32
// needs ~130 live). JW=16 fits 64 regs (R11/R12 evidence: WRITE ~32KB-3MB).

#define NPTS 1024
#define FDIM 64
#define RDIM 8
#define HID  128
#define NTH  1024
#define NW   16
#define JW   16
#define NPASS (NPTS / (NW * JW))   // 4
#define EPS_F 0.1f
#define INV_EPS 10.0f
#define LOG2E 1.44269504088896340736f
#define LN2   0.69314718055994530942f

typedef __attribute__((ext_vector_type(8))) short short8;   // 8 bf16
typedef __attribute__((ext_vector_type(4))) float f32x4;

// LDS byte offsets
#define OFF_WF1  0         // 65536: W1 frags [mt8][ks4][hi/lo][lane*16]
#define OFF_WF2  65536     // 65536: W2 frags (rho-permuted k rows)
#define OFF_STG  131072    // 16384: init staging chunk (32 rows x 128 f32)
#define OFF_HXI  147456    // 512
#define OFF_B1   147968    // 512
#define OFF_B2   148480    // 512
#define OFF_WOUT 148992    // 512
#define OFF_W0R  149504    // 4096 (fallback only)
#define OFF_LSE  153600    // 128 (16 waves x {m,s})
#define LDS_BYTES 153728   // < 163840

// exp2-domain softplus: sp(x) = ln2 * sp2(x*log2e); scales folded at staging.
__device__ __forceinline__ float sp2(float t) {
    float z;
    asm("v_exp_f32_e64 %0, -abs(%1)" : "=v"(z) : "v"(t));  // 2^(-|t|)
    z += 1.0f;
    float r;
    asm("v_log_f32 %0, %1" : "=v"(r) : "v"(z));            // log2(1+2^-|t|)
    return fmaxf(t, 0.0f) + r;
}
__device__ __forceinline__ float bcf(unsigned x) { return __builtin_bit_cast(float, x); }
__device__ __forceinline__ unsigned short bf16c(float x) {
    return __builtin_bit_cast(unsigned short, __float2bfloat16(x));
}
// hi/lo split (W staging only): hi = bf16(x), lo = bf16(x - hi).
__device__ __forceinline__ void hilo(float x, unsigned short& h, unsigned short& l) {
    h = bf16c(x);
    l = bf16c(x - bcf(((unsigned)h) << 16));
}

// pre-kernel (exp2-domain: outputs pre-scaled by log2e):
// hX[n][c] natural; hY in frag-read layout hYP[(n>>4)*2048+(c>>2)*64+(n&15)*4+(c&3)]
__global__ void eotqr_pre(const float* __restrict__ Xg, const float* __restrict__ Yg,
                          const float* __restrict__ W0g, const float* __restrict__ b0g,
                          float* __restrict__ hX, float* __restrict__ hYP) {
    const int n = blockIdx.x, c = threadIdx.x;
    float a = b0g[c];
    for (int f = 0; f < FDIM; ++f) a += Xg[n * FDIM + f] * W0g[f * HID + c];
    hX[n * HID + c] = a * LOG2E;
    float b = 0.0f;
#pragma unroll
    for (int r = 0; r < RDIM; ++r) b += Yg[n * RDIM + r] * W0g[(FDIM + r) * HID + c];
    hYP[(n >> 4) * 2048 + (c >> 2) * 64 + (n & 15) * 4 + (c & 3)] = b * LOG2E;
}

// Stage one layer's W into frag-linear LDS (W frags NOT scaled — the ln2*log2e
// between consecutive sp' layers cancels). Waves 0..7 build mt=wid.
#define STAGE_LAYER(WSRC, WFBASE, IS_W2)                                      \
    for (int r = 0; r < 4; ++r) {                                             \
        __syncthreads();                                                      \
        for (int e4 = tid; e4 < 1024; e4 += NTH)                              \
            ((float4*)(smem + OFF_STG))[e4] =                                 \
                ((const float4*)((WSRC) + r * 32 * HID))[e4];                 \
        __syncthreads();                                                      \
        if (wid < 8) {                                                        \
            const float* stg = (const float*)(smem + OFF_STG);                \
            const int mt = wid;                                               \
            union { unsigned short u[8]; short8 v; } ph, pl;                  \
            _Pragma("unroll")                                                 \
            for (int e = 0; e < 8; ++e) {                                     \
                const int kloc = (IS_W2) ? ((e >= 4) * 16 + g * 4 + (e & 3))  \
                                         : (g * 8 + e);                       \
                hilo(stg[kloc * HID + mt * 16 + (lane & 15)], ph.u[e], pl.u[e]); \
            }                                                                 \
            *(short8*)(smem + (WFBASE) + ((mt * 4 + r) * 2 + 0) * 1024 + lane * 16) = ph.v; \
            *(short8*)(smem + (WFBASE) + ((mt * 4 + r) * 2 + 1) * 1024 + lane * 16) = pl.v; \
        }                                                                     \
    }

// 2-product: (Whi + Wlo) x H. Per-mt reorder fence bounds ds_read hoisting.
#define GEMM_LAYER(WFBASE)                                                    \
    _Pragma("unroll")                                                         \
    for (int mt = 0; mt < 8; ++mt) acc[mt] = f32x4{0.f, 0.f, 0.f, 0.f};       \
    _Pragma("unroll")                                                         \
    for (int mt = 0; mt < 8; ++mt) {                                          \
        _Pragma("unroll")                                                     \
        for (int ks = 0; ks < 4; ++ks) {                                      \
            const short8 ah = *(const short8*)(smem + (WFBASE) + ((mt * 4 + ks) * 2 + 0) * 1024 + lane * 16); \
            const short8 al = *(const short8*)(smem + (WFBASE) + ((mt * 4 + ks) * 2 + 1) * 1024 + lane * 16); \
            acc[mt] = __builtin_amdgcn_mfma_f32_16x16x32_bf16(ah, bh[ks], acc[mt], 0, 0, 0); \
            acc[mt] = __builtin_amdgcn_mfma_f32_16x16x32_bf16(al, bh[ks], acc[mt], 0, 0, 0); \
        }                                                                     \
        asm volatile("" ::: "memory");                                        \
    }

template <bool USE_WS>
__global__
__attribute__((amdgpu_flat_work_group_size(NTH, NTH)))
__attribute__((amdgpu_waves_per_eu(2, 4)))
void eotqr_mfma(const float* __restrict__ Xg, const float* __restrict__ Ug,
                const float* __restrict__ Yg, const float* __restrict__ W0g,
                const float* __restrict__ b0g, const float* __restrict__ W1g,
                const float* __restrict__ b1g, const float* __restrict__ W2g,
                const float* __restrict__ b2g, const float* __restrict__ Woutg,
                const float* __restrict__ boutg, const float* __restrict__ hXg,
                const float* __restrict__ hYg, float* __restrict__ outg) {
    __shared__ __align__(16) char smem[LDS_BYTES];
    const int tid  = threadIdx.x;
    const int i    = blockIdx.x;
    const int lane = tid & 63;
    const int wid  = tid >> 6;      // 0..15
    const int g    = lane >> 4;

    // ---- init: small tables (exp2-domain scaling folded here) ----
    if (tid < HID) {
        ((float*)(smem + OFF_B1))[tid]   = b1g[tid] * LOG2E;
        ((float*)(smem + OFF_B2))[tid]   = b2g[tid] * LOG2E;
        ((float*)(smem + OFF_WOUT))[tid] = Woutg[tid] * LN2;
        float a;
        if (USE_WS) {
            a = hXg[i * HID + tid];           // pre-scaled in pre-kernel
        } else {
            a = b0g[tid];
            for (int f = 0; f < FDIM; ++f) a += Xg[i * FDIM + f] * W0g[f * HID + tid];
            a *= LOG2E;
        }
        ((float*)(smem + OFF_HXI))[tid] = a;
    }
    if (!USE_WS)
        for (int e = tid; e < RDIM * HID; e += NTH)
            ((float*)(smem + OFF_W0R))[e] = W0g[FDIM * HID + e] * LOG2E;

    // ---- stage W frags ----
    STAGE_LAYER(W1g, OFF_WF1, 0)
    STAGE_LAYER(W2g, OFF_WF2, 1)
    __syncthreads();

    const float bout0 = boutg[0];
    float Ui[RDIM];
#pragma unroll
    for (int r = 0; r < RDIM; ++r) Ui[r] = Ug[i * RDIM + r];

    float m_run = -INFINITY, s_run = 0.0f;

#pragma unroll 1
    for (int p = 0; p < NPASS; ++p) {
        const int jme = p * (NW * JW) + wid * JW + (lane & 15);
        const float4 ya = *(const float4*)(Yg + jme * RDIM);
        const float4 yb = *(const float4*)(Yg + jme * RDIM + 4);

        // ---- layer 0: B1 frags (single bf16) ----
        short8 bh[4];
#pragma unroll
        for (int ks = 0; ks < 4; ++ks) {
            float s[8];
            if (USE_WS) {
                const float* hb = hYg + (size_t)(p * NW + wid) * 2048 + (lane & 15) * 4;
                const float4 q0 = *(const float4*)(hb + (8 * ks + 2 * g + 0) * 64);
                const float4 q1 = *(const float4*)(hb + (8 * ks + 2 * g + 1) * 64);
                s[0] = q0.x; s[1] = q0.y; s[2] = q0.z; s[3] = q0.w;
                s[4] = q1.x; s[5] = q1.y; s[6] = q1.z; s[7] = q1.w;
            } else {
                const float* w0r = (const float*)(smem + OFF_W0R);
                const float yv[8] = {ya.x, ya.y, ya.z, ya.w, yb.x, yb.y, yb.z, yb.w};
#pragma unroll
                for (int e = 0; e < 8; ++e) {
                    float b = 0.0f;
#pragma unroll
                    for (int r = 0; r < RDIM; ++r)
                        b += yv[r] * w0r[r * HID + 32 * ks + 8 * g + e];
                    s[e] = b;
                }
            }
            const float4 hx0 = *(const float4*)(smem + OFF_HXI + (32 * ks + 8 * g) * 4);
            const float4 hx1 = *(const float4*)(smem + OFF_HXI + (32 * ks + 8 * g) * 4 + 16);
            s[0] += hx0.x; s[1] += hx0.y; s[2] += hx0.z; s[3] += hx0.w;
            s[4] += hx1.x; s[5] += hx1.y; s[6] += hx1.z; s[7] += hx1.w;
            union { unsigned short u[8]; short8 v; } ph;
#pragma unroll
            for (int e = 0; e < 8; ++e) ph.u[e] = bf16c(sp2(s[e]));
            bh[ks] = ph.v;
        }

        f32x4 acc[8];
        // ---- layer 1 ----
        GEMM_LAYER(OFF_WF1)

        // ---- epi1: C-frags -> B2 frags in-lane (rho at W2 staging) ----
#pragma unroll
        for (int ks = 0; ks < 4; ++ks) {
            union { unsigned short u[8]; short8 v; } ph;
#pragma unroll
            for (int b = 0; b < 2; ++b) {
                const int mt = 2 * ks + b;
                const float4 bias = *(const float4*)(smem + OFF_B1 + (mt * 16 + 4 * g) * 4);
                const float bv[4] = {bias.x, bias.y, bias.z, bias.w};
#pragma unroll
                for (int e2 = 0; e2 < 4; ++e2)
                    ph.u[b * 4 + e2] = bf16c(sp2(acc[mt][e2] + bv[e2]));
            }
            bh[ks] = ph.v;
        }

        // ---- layer 2 ----
        GEMM_LAYER(OFF_WF2)

        // ---- epi2: psi partial (wouts pre-scaled by ln2) ----
        float ps = 0.0f;
#pragma unroll
        for (int mt = 0; mt < 8; ++mt) {
            const float4 b2v = *(const float4*)(smem + OFF_B2 + (mt * 16 + 4 * g) * 4);
            const float4 wov = *(const float4*)(smem + OFF_WOUT + (mt * 16 + 4 * g) * 4);
            const float bv[4] = {b2v.x, b2v.y, b2v.z, b2v.w};
            const float wv[4] = {wov.x, wov.y, wov.z, wov.w};
#pragma unroll
            for (int e2 = 0; e2 < 4; ++e2)
                ps += sp2(acc[mt][e2] + bv[e2]) * wv[e2];
        }
        ps += __shfl_xor(ps, 16);
        ps += __shfl_xor(ps, 32);   // full 128-row sum; all lanes hold psi[j]

        float cost = Ui[0] * ya.x + Ui[1] * ya.y + Ui[2] * ya.z + Ui[3] * ya.w +
                     Ui[4] * yb.x + Ui[5] * yb.y + Ui[6] * yb.z + Ui[7] * yb.w;
        const float slk = cost - ps - bout0;

        // ---- online LSE within the 16-lane group ----
        float t = slk;
#pragma unroll
        for (int d = 1; d <= 8; d <<= 1) t = fmaxf(t, __shfl_xor(t, d));
        const float nm = fmaxf(m_run, t);
        float e = __expf((slk - nm) * INV_EPS);
#pragma unroll
        for (int d = 1; d <= 8; d <<= 1) e += __shfl_xor(e, d);
        s_run = s_run * __expf((m_run - nm) * INV_EPS) + e;
        m_run = nm;
    }

    // ---- cross-wave combine ----
    if (lane == 0) {
        ((float*)(smem + OFF_LSE))[wid]      = m_run;
        ((float*)(smem + OFF_LSE))[NW + wid] = s_run;
    }
    __syncthreads();
    if (tid == 0) {
        const float* lm = (const float*)(smem + OFF_LSE);
        float M = -INFINITY;
#pragma unroll
        for (int w = 0; w < NW; ++w) M = fmaxf(M, lm[w]);
        float S = 0.0f;
#pragma unroll
        for (int w = 0; w < NW; ++w) S += lm[NW + w] * __expf((lm[w] - M) * INV_EPS);
        outg[i] = EPS_F * (logf(S) - logf((float)NPTS)) + M;
    }
}

extern "C" void kernel_launch(void* const* d_in, const int* in_sizes, int n_in,
                              void* d_out, int out_size, void* d_ws, size_t ws_size,
                              hipStream_t stream) {
    const float* X    = (const float*)d_in[0];
    const float* U    = (const float*)d_in[1];
    const float* Y    = (const float*)d_in[2];
    const float* W0   = (const float*)d_in[3];
    const float* b0   = (const float*)d_in[4];
    const float* W1   = (const float*)d_in[5];
    const float* b1   = (const float*)d_in[6];
    const float* W2   = (const float*)d_in[7];
    const float* b2   = (const float*)d_in[8];
    const float* Wout = (const float*)d_in[9];
    const float* bout = (const float*)d_in[10];
    float* out = (float*)d_out;

    const size_t need_ws = (size_t)2 * NPTS * HID * sizeof(float);  // 1 MiB
    if (ws_size >= need_ws) {
        float* hX  = (float*)d_ws;
        float* hYP = hX + NPTS * HID;
        hipLaunchKernelGGL(eotqr_pre, dim3(NPTS), dim3(HID), 0, stream, X, Y, W0, b0, hX, hYP);
        hipLaunchKernelGGL(eotqr_mfma<true>, dim3(NPTS), dim3(NTH), 0, stream,
                           X, U, Y, W0, b0, W1, b1, W2, b2, Wout, bout, hX, hYP, out);
    } else {
        hipLaunchKernelGGL(eotqr_mfma<false>, dim3(NPTS), dim3(NTH), 0, stream,
                           X, U, Y, W0, b0, W1, b1, W2, b2, Wout, bout,
                           (const float*)nullptr, (const float*)nullptr, out);
    }
}

// Round 15
// 206.258 us; speedup vs baseline: 8.8608x; 1.0276x over previous
//
#include <hip/hip_runtime.h>
#include <hip/hip_bf16.h>

// EntropicOTQuantileRegression — R15. Single variable vs R14: fuse the
// f32->bf16 convert + pair-merge using v_cvt_pk_bf16_f32 (one inst replaces
// 2 cvts + union merge) in layer-0 and epi-1. Scalar-operand asm only.
// Decision rule: null result => issue-port roofline (88% util), stop.

#define NPTS 1024
#define FDIM 64
#define RDIM 8
#define HID  128
#define NTH  1024
#define NW   16
#define JW   16
#define NPASS (NPTS / (NW * JW))   // 4
#define EPS_F 0.1f
#define INV_EPS 10.0f
#define LOG2E 1.44269504088896340736f
#define LN2   0.69314718055994530942f

typedef __attribute__((ext_vector_type(8))) short short8;   // 8 bf16
typedef __attribute__((ext_vector_type(4))) float f32x4;

// LDS byte offsets
#define OFF_WF1  0         // 65536: W1 frags [mt8][ks4][hi/lo][lane*16]
#define OFF_WF2  65536     // 65536: W2 frags (rho-permuted k rows)
#define OFF_STG  131072    // 16384: init staging chunk (32 rows x 128 f32)
#define OFF_HXI  147456    // 512
#define OFF_B1   147968    // 512
#define OFF_B2   148480    // 512
#define OFF_WOUT 148992    // 512
#define OFF_W0R  149504    // 4096 (fallback only)
#define OFF_LSE  153600    // 128 (16 waves x {m,s})
#define LDS_BYTES 153728   // < 163840

// exp2-domain softplus: sp(x) = ln2 * sp2(x*log2e); scales folded at staging.
__device__ __forceinline__ float sp2(float t) {
    float z;
    asm("v_exp_f32_e64 %0, -abs(%1)" : "=v"(z) : "v"(t));  // 2^(-|t|)
    z += 1.0f;
    float r;
    asm("v_log_f32 %0, %1" : "=v"(r) : "v"(z));            // log2(1+2^-|t|)
    return fmaxf(t, 0.0f) + r;
}
// sp2 on a pair + fused bf16 pack: lo half = sp2(a), hi half = sp2(b).
__device__ __forceinline__ unsigned sp2_pk(float a, float b) {
    const float ra = sp2(a), rb = sp2(b);
    unsigned out;
    asm("v_cvt_pk_bf16_f32 %0, %1, %2" : "=v"(out) : "v"(ra), "v"(rb));
    return out;
}
__device__ __forceinline__ float bcf(unsigned x) { return __builtin_bit_cast(float, x); }
__device__ __forceinline__ unsigned short bf16c(float x) {
    return __builtin_bit_cast(unsigned short, __float2bfloat16(x));
}
// hi/lo split (W staging only): hi = bf16(x), lo = bf16(x - hi).
__device__ __forceinline__ void hilo(float x, unsigned short& h, unsigned short& l) {
    h = bf16c(x);
    l = bf16c(x - bcf(((unsigned)h) << 16));
}

// pre-kernel (exp2-domain: outputs pre-scaled by log2e):
// hX[n][c] natural; hY in frag-read layout hYP[(n>>4)*2048+(c>>2)*64+(n&15)*4+(c&3)]
__global__ void eotqr_pre(const float* __restrict__ Xg, const float* __restrict__ Yg,
                          const float* __restrict__ W0g, const float* __restrict__ b0g,
                          float* __restrict__ hX, float* __restrict__ hYP) {
    const int n = blockIdx.x, c = threadIdx.x;
    float a = b0g[c];
    for (int f = 0; f < FDIM; ++f) a += Xg[n * FDIM + f] * W0g[f * HID + c];
    hX[n * HID + c] = a * LOG2E;
    float b = 0.0f;
#pragma unroll
    for (int r = 0; r < RDIM; ++r) b += Yg[n * RDIM + r] * W0g[(FDIM + r) * HID + c];
    hYP[(n >> 4) * 2048 + (c >> 2) * 64 + (n & 15) * 4 + (c & 3)] = b * LOG2E;
}

// Stage one layer's W into frag-linear LDS (W frags NOT scaled — the ln2*log2e
// between consecutive sp' layers cancels). Waves 0..7 build mt=wid.
#define STAGE_LAYER(WSRC, WFBASE, IS_W2)                                      \
    for (int r = 0; r < 4; ++r) {                                             \
        __syncthreads();                                                      \
        for (int e4 = tid; e4 < 1024; e4 += NTH)                              \
            ((float4*)(smem + OFF_STG))[e4] =                                 \
                ((const float4*)((WSRC) + r * 32 * HID))[e4];                 \
        __syncthreads();                                                      \
        if (wid < 8) {                                                        \
            const float* stg = (const float*)(smem + OFF_STG);                \
            const int mt = wid;                                               \
            union { unsigned short u[8]; short8 v; } ph, pl;                  \
            _Pragma("unroll")                                                 \
            for (int e = 0; e < 8; ++e) {                                     \
                const int kloc = (IS_W2) ? ((e >= 4) * 16 + g * 4 + (e & 3))  \
                                         : (g * 8 + e);                       \
                hilo(stg[kloc * HID + mt * 16 + (lane & 15)], ph.u[e], pl.u[e]); \
            }                                                                 \
            *(short8*)(smem + (WFBASE) + ((mt * 4 + r) * 2 + 0) * 1024 + lane * 16) = ph.v; \
            *(short8*)(smem + (WFBASE) + ((mt * 4 + r) * 2 + 1) * 1024 + lane * 16) = pl.v; \
        }                                                                     \
    }

// 2-product: (Whi + Wlo) x H. Per-mt reorder fence bounds ds_read hoisting.
#define GEMM_LAYER(WFBASE)                                                    \
    _Pragma("unroll")                                                         \
    for (int mt = 0; mt < 8; ++mt) acc[mt] = f32x4{0.f, 0.f, 0.f, 0.f};       \
    _Pragma("unroll")                                                         \
    for (int mt = 0; mt < 8; ++mt) {                                          \
        _Pragma("unroll")                                                     \
        for (int ks = 0; ks < 4; ++ks) {                                      \
            const short8 ah = *(const short8*)(smem + (WFBASE) + ((mt * 4 + ks) * 2 + 0) * 1024 + lane * 16); \
            const short8 al = *(const short8*)(smem + (WFBASE) + ((mt * 4 + ks) * 2 + 1) * 1024 + lane * 16); \
            acc[mt] = __builtin_amdgcn_mfma_f32_16x16x32_bf16(ah, bh[ks], acc[mt], 0, 0, 0); \
            acc[mt] = __builtin_amdgcn_mfma_f32_16x16x32_bf16(al, bh[ks], acc[mt], 0, 0, 0); \
        }                                                                     \
        asm volatile("" ::: "memory");                                        \
    }

template <bool USE_WS>
__global__
__attribute__((amdgpu_flat_work_group_size(NTH, NTH)))
__attribute__((amdgpu_waves_per_eu(2, 4)))
void eotqr_mfma(const float* __restrict__ Xg, const float* __restrict__ Ug,
                const float* __restrict__ Yg, const float* __restrict__ W0g,
                const float* __restrict__ b0g, const float* __restrict__ W1g,
                const float* __restrict__ b1g, const float* __restrict__ W2g,
                const float* __restrict__ b2g, const float* __restrict__ Woutg,
                const float* __restrict__ boutg, const float* __restrict__ hXg,
                const float* __restrict__ hYg, float* __restrict__ outg) {
    __shared__ __align__(16) char smem[LDS_BYTES];
    const int tid  = threadIdx.x;
    const int i    = blockIdx.x;
    const int lane = tid & 63;
    const int wid  = tid >> 6;      // 0..15
    const int g    = lane >> 4;

    // ---- init: small tables (exp2-domain scaling folded here) ----
    if (tid < HID) {
        ((float*)(smem + OFF_B1))[tid]   = b1g[tid] * LOG2E;
        ((float*)(smem + OFF_B2))[tid]   = b2g[tid] * LOG2E;
        ((float*)(smem + OFF_WOUT))[tid] = Woutg[tid] * LN2;
        float a;
        if (USE_WS) {
            a = hXg[i * HID + tid];           // pre-scaled in pre-kernel
        } else {
            a = b0g[tid];
            for (int f = 0; f < FDIM; ++f) a += Xg[i * FDIM + f] * W0g[f * HID + tid];
            a *= LOG2E;
        }
        ((float*)(smem + OFF_HXI))[tid] = a;
    }
    if (!USE_WS)
        for (int e = tid; e < RDIM * HID; e += NTH)
            ((float*)(smem + OFF_W0R))[e] = W0g[FDIM * HID + e] * LOG2E;

    // ---- stage W frags ----
    STAGE_LAYER(W1g, OFF_WF1, 0)
    STAGE_LAYER(W2g, OFF_WF2, 1)
    __syncthreads();

    const float bout0 = boutg[0];
    float Ui[RDIM];
#pragma unroll
    for (int r = 0; r < RDIM; ++r) Ui[r] = Ug[i * RDIM + r];

    float m_run = -INFINITY, s_run = 0.0f;

#pragma unroll 1
    for (int p = 0; p < NPASS; ++p) {
        const int jme = p * (NW * JW) + wid * JW + (lane & 15);
        const float4 ya = *(const float4*)(Yg + jme * RDIM);
        const float4 yb = *(const float4*)(Yg + jme * RDIM + 4);

        // ---- layer 0: B1 frags (single bf16, pk-fused conversion) ----
        short8 bh[4];
#pragma unroll
        for (int ks = 0; ks < 4; ++ks) {
            float s[8];
            if (USE_WS) {
                const float* hb = hYg + (size_t)(p * NW + wid) * 2048 + (lane & 15) * 4;
                const float4 q0 = *(const float4*)(hb + (8 * ks + 2 * g + 0) * 64);
                const float4 q1 = *(const float4*)(hb + (8 * ks + 2 * g + 1) * 64);
                s[0] = q0.x; s[1] = q0.y; s[2] = q0.z; s[3] = q0.w;
                s[4] = q1.x; s[5] = q1.y; s[6] = q1.z; s[7] = q1.w;
            } else {
                const float* w0r = (const float*)(smem + OFF_W0R);
                const float yv[8] = {ya.x, ya.y, ya.z, ya.w, yb.x, yb.y, yb.z, yb.w};
#pragma unroll
                for (int e = 0; e < 8; ++e) {
                    float b = 0.0f;
#pragma unroll
                    for (int r = 0; r < RDIM; ++r)
                        b += yv[r] * w0r[r * HID + 32 * ks + 8 * g + e];
                    s[e] = b;
                }
            }
            const float4 hx0 = *(const float4*)(smem + OFF_HXI + (32 * ks + 8 * g) * 4);
            const float4 hx1 = *(const float4*)(smem + OFF_HXI + (32 * ks + 8 * g) * 4 + 16);
            s[0] += hx0.x; s[1] += hx0.y; s[2] += hx0.z; s[3] += hx0.w;
            s[4] += hx1.x; s[5] += hx1.y; s[6] += hx1.z; s[7] += hx1.w;
            union { unsigned w[4]; short8 v; } ph;
#pragma unroll
            for (int e = 0; e < 8; e += 2)
                ph.w[e >> 1] = sp2_pk(s[e], s[e + 1]);
            bh[ks] = ph.v;
        }

        f32x4 acc[8];
        // ---- layer 1 ----
        GEMM_LAYER(OFF_WF1)

        // ---- epi1: C-frags -> B2 frags in-lane (rho at W2 staging) ----
#pragma unroll
        for (int ks = 0; ks < 4; ++ks) {
            union { unsigned w[4]; short8 v; } ph;
#pragma unroll
            for (int b = 0; b < 2; ++b) {
                const int mt = 2 * ks + b;
                const float4 bias = *(const float4*)(smem + OFF_B1 + (mt * 16 + 4 * g) * 4);
                ph.w[b * 2 + 0] = sp2_pk(acc[mt][0] + bias.x, acc[mt][1] + bias.y);
                ph.w[b * 2 + 1] = sp2_pk(acc[mt][2] + bias.z, acc[mt][3] + bias.w);
            }
            bh[ks] = ph.v;
        }

        // ---- layer 2 ----
        GEMM_LAYER(OFF_WF2)

        // ---- epi2: psi partial (wouts pre-scaled by ln2) ----
        float ps = 0.0f;
#pragma unroll
        for (int mt = 0; mt < 8; ++mt) {
            const float4 b2v = *(const float4*)(smem + OFF_B2 + (mt * 16 + 4 * g) * 4);
            const float4 wov = *(const float4*)(smem + OFF_WOUT + (mt * 16 + 4 * g) * 4);
            const float bv[4] = {b2v.x, b2v.y, b2v.z, b2v.w};
            const float wv[4] = {wov.x, wov.y, wov.z, wov.w};
#pragma unroll
            for (int e2 = 0; e2 < 4; ++e2)
                ps += sp2(acc[mt][e2] + bv[e2]) * wv[e2];
        }
        ps += __shfl_xor(ps, 16);
        ps += __shfl_xor(ps, 32);   // full 128-row sum; all lanes hold psi[j]

        float cost = Ui[0] * ya.x + Ui[1] * ya.y + Ui[2] * ya.z + Ui[3] * ya.w +
                     Ui[4] * yb.x + Ui[5] * yb.y + Ui[6] * yb.z + Ui[7] * yb.w;
        const float slk = cost - ps - bout0;

        // ---- online LSE within the 16-lane group ----
        float t = slk;
#pragma unroll
        for (int d = 1; d <= 8; d <<= 1) t = fmaxf(t, __shfl_xor(t, d));
        const float nm = fmaxf(m_run, t);
        float e = __expf((slk - nm) * INV_EPS);
#pragma unroll
        for (int d = 1; d <= 8; d <<= 1) e += __shfl_xor(e, d);
        s_run = s_run * __expf((m_run - nm) * INV_EPS) + e;
        m_run = nm;
    }

    // ---- cross-wave combine ----
    if (lane == 0) {
        ((float*)(smem + OFF_LSE))[wid]      = m_run;
        ((float*)(smem + OFF_LSE))[NW + wid] = s_run;
    }
    __syncthreads();
    if (tid == 0) {
        const float* lm = (const float*)(smem + OFF_LSE);
        float M = -INFINITY;
#pragma unroll
        for (int w = 0; w < NW; ++w) M = fmaxf(M, lm[w]);
        float S = 0.0f;
#pragma unroll
        for (int w = 0; w < NW; ++w) S += lm[NW + w] * __expf((lm[w] - M) * INV_EPS);
        outg[i] = EPS_F * (logf(S) - logf((float)NPTS)) + M;
    }
}

extern "C" void kernel_launch(void* const* d_in, const int* in_sizes, int n_in,
                              void* d_out, int out_size, void* d_ws, size_t ws_size,
                              hipStream_t stream) {
    const float* X    = (const float*)d_in[0];
    const float* U    = (const float*)d_in[1];
    const float* Y    = (const float*)d_in[2];
    const float* W0   = (const float*)d_in[3];
    const float* b0   = (const float*)d_in[4];
    const float* W1   = (const float*)d_in[5];
    const float* b1   = (const float*)d_in[6];
    const float* W2   = (const float*)d_in[7];
    const float* b2   = (const float*)d_in[8];
    const float* Wout = (const float*)d_in[9];
    const float* bout = (const float*)d_in[10];
    float* out = (float*)d_out;

    const size_t need_ws = (size_t)2 * NPTS * HID * sizeof(float);  // 1 MiB
    if (ws_size >= need_ws) {
        float* hX  = (float*)d_ws;
        float* hYP = hX + NPTS * HID;
        hipLaunchKernelGGL(eotqr_pre, dim3(NPTS), dim3(HID), 0, stream, X, Y, W0, b0, hX, hYP);
        hipLaunchKernelGGL(eotqr_mfma<true>, dim3(NPTS), dim3(NTH), 0, stream,
                           X, U, Y, W0, b0, W1, b1, W2, b2, Wout, bout, hX, hYP, out);
    } else {
        hipLaunchKernelGGL(eotqr_mfma<false>, dim3(NPTS), dim3(NTH), 0, stream,
                           X, U, Y, W0, b0, W1, b1, W2, b2, Wout, bout,
                           (const float*)nullptr, (const float*)nullptr, out);
    }
}